// Round 10
// baseline (4210.600 us; speedup 1.0000x reference)
//
#include <hip/hip_runtime.h>

typedef unsigned short u16;
typedef unsigned int u32;
typedef __attribute__((ext_vector_type(8))) short bf16x8;
typedef __attribute__((ext_vector_type(8))) _Float16 f16x8;
typedef __attribute__((ext_vector_type(4))) float f32x4;

// ---------------------------------------------------------------------------
// Problem constants
// ---------------------------------------------------------------------------
constexpr int Bq = 4, Sq = 4096, Dq = 1024, Hq = 16, Eq = 8, HIDq = 4096;
constexpr int Tq = Bq * Sq;               // 16384 tokens
constexpr long TD = (long)Tq * Dq;        // 16,777,216
constexpr int PADT = 33792;               // padded MoE slots cap
constexpr int QCN  = 1024;                // seq chunk for qkv/attn
constexpr int QROWS = 4 * QCN;
constexpr int ECH  = 4096;                // MoE expert-chunk rows
constexpr int MAXC = 3;                   // chunks per expert (cap 12288)

// ---------------------------------------------------------------------------
// Workspace layout (unchanged, proven safe).
// ---------------------------------------------------------------------------
constexpr long OFF_XC = 262144;                        // floats
constexpr long OFF_Q  = OFF_XC + TD;                   // floats
constexpr long OFF_WT = OFF_Q + (long)QROWS * 3 * Dq;  // floats
constexpr long H_B    = OFF_Q * 4;                     // bytes
constexpr long W1E_B  = H_B + (long)2 * ECH * HIDq;    // +33,554,432
constexpr long W2E_B  = W1E_B + (long)2 * Dq * HIDq;   // +8,388,608

// ---------------------------------------------------------------------------
// bf16 helpers (RNE)
// ---------------------------------------------------------------------------
__device__ __forceinline__ u32 bf1(float x) {
  u32 u = __builtin_bit_cast(u32, x);
  return (u + 0x7fffu + ((u >> 16) & 1u)) >> 16;
}
__device__ __forceinline__ u32 bfpk(float lo, float hi) {
  return bf1(lo) | (bf1(hi) << 16);
}

// ---------------------------------------------------------------------------
// f16 split helpers: a = ah + al*2^-12; al stored pre-scaled by 2^12.
// ---------------------------------------------------------------------------
__device__ __forceinline__ u16 f16b(float v) {
  _Float16 h = (_Float16)v;
  return __builtin_bit_cast(u16, h);
}
// A-side cross pair: [al_s | ah<<16]
__device__ __forceinline__ u32 axpk(float v) {
  _Float16 h = (_Float16)v;
  float hf = (float)h;
  u16 l = f16b((v - hf) * 4096.0f);
  return (u32)l | ((u32)__builtin_bit_cast(u16, h) << 16);
}
// B-side stored pair: [bh | bl_s<<16]
__device__ __forceinline__ u32 bxpk(float v) {
  _Float16 h = (_Float16)v;
  float hf = (float)h;
  u16 l = f16b((v - hf) * 4096.0f);
  return (u32)__builtin_bit_cast(u16, h) | ((u32)l << 16);
}

#define BM 128
#define BN 128

// async global->LDS, 16B per lane (dest = wave-uniform base + lane*16)
#define GLL16(SRC, DST)                                                \
  __builtin_amdgcn_global_load_lds(                                    \
      (const __attribute__((address_space(1))) void*)(SRC),            \
      (__attribute__((address_space(3))) void*)(DST), 16, 0, 0)

// ---------------------------------------------------------------------------
// XCD-aware block swizzle (kept: FETCH 807->230 MB measured R9).
// ---------------------------------------------------------------------------
__device__ __forceinline__ void xcd_swz(int& bx, int& by) {
  const int nbx = (int)gridDim.x;
  const int nwg = nbx * (int)gridDim.y;
  int bid = (int)blockIdx.y * nbx + (int)blockIdx.x;
  bid = (bid & 7) * (nwg >> 3) + (bid >> 3);
  bx = bid % nbx;
  by = bid / nbx;
}

// ---------------------------------------------------------------------------
// Octet extraction from split-pair quads in LDS.
// ---------------------------------------------------------------------------
__device__ __forceinline__ f16x8 hi_octet(const u16* p) {
  const uint4 a = *(const uint4*)p;
  const uint4 b = *(const uint4*)(p + 1024);  // next quad-row block
  uint4 r;
  r.x = __builtin_amdgcn_perm(a.y, a.x, 0x07060302u);
  r.y = __builtin_amdgcn_perm(a.w, a.z, 0x07060302u);
  r.z = __builtin_amdgcn_perm(b.y, b.x, 0x07060302u);
  r.w = __builtin_amdgcn_perm(b.w, b.z, 0x07060302u);
  return __builtin_bit_cast(f16x8, r);
}
__device__ __forceinline__ f16x8 lo_octet(const u16* p) {
  const uint4 a = *(const uint4*)p;
  const uint4 b = *(const uint4*)(p + 1024);
  uint4 r;
  r.x = __builtin_amdgcn_perm(a.y, a.x, 0x05040100u);
  r.y = __builtin_amdgcn_perm(a.w, a.z, 0x05040100u);
  r.z = __builtin_amdgcn_perm(b.y, b.x, 0x05040100u);
  r.w = __builtin_amdgcn_perm(b.w, b.z, 0x05040100u);
  return __builtin_bit_cast(f16x8, r);
}

// ===========================================================================
// f16 split-precision MFMA GEMM, SINGLE-PASS + SOFTWARE-PIPELINED STAGING:
//   - A prefetched into registers one step ahead (issued during MFMA phase;
//     reg loads survive barriers un-drained).
//   - B staged via async global_load_lds into a DOUBLE-BUFFERED Bsx, issued
//     at MFMA-phase start into buf^1; drained by the tail barrier (hidden
//     under ~48 MFMAs).
// Numerics bit-identical to R5's verified kernel (same MFMA values/order).
// AMODE: 0 direct rows | 1 conv-gather from x | 4 qkv-chunk gather from xc
// EPI:   0 bias store | 2 bias + C_old accumulate store
// ===========================================================================
template <int AMODE, int EPI>
__global__ __launch_bounds__(256, 2) void gemm_h(
    const float* __restrict__ A, const u16* __restrict__ Bx,
    const float* __restrict__ bias, float* __restrict__ C,
    int Ko, int lda, int ldbN, int ldc, int nbase) {
  // quad-granular layouts: [quad 0..7][row 0..127][8 u16 = 4 pairs]
  __shared__ __align__(16) u16 Asx[8 * 128 * 8];
  __shared__ __align__(16) u16 Bsx[2][8 * 128 * 8];

  const int tid = threadIdx.x;
  int sbx, sby;
  xcd_swz(sbx, sby);
  const int m0 = sby * BM;
  const int n0 = sbx * BN;

  const float* arp[2];
  int abat[2], asrow[2];
  #pragma unroll
  for (int i = 0; i < 2; i++) {
    const int f = tid + 256 * i;
    const int m = f >> 2;
    if (AMODE == 0) {
      arp[i] = A + (long)(m0 + m) * lda;
    } else if (AMODE == 1) {
      abat[i] = (m0 + m) >> 12;
      asrow[i] = (m0 + m) & 4095;
    } else {  // AMODE == 4
      const int mm = m0 + m;
      const int l = mm >> 10;
      const int n = nbase + (mm & 1023);
      arp[i] = A + (long)(l * Sq + n) * lda;
    }
  }

  f32x4 acch[4][4], accx[4][4];
  #pragma unroll
  for (int i = 0; i < 4; i++)
    #pragma unroll
    for (int j = 0; j < 4; j++) {
      acch[i][j] = (f32x4)(0.f);
      accx[i][j] = (f32x4)(0.f);
    }

  const int lane = tid & 63;
  const int wave = tid >> 6;
  const int wr = wave >> 1, wc = wave & 1;
  const int q = lane >> 4, l16 = lane & 15;
  const int abase = wr * 64 + l16;
  const int bbase = wc * 64 + l16;

  // A-step load into registers (8 fp32 per thread-iter, 16 VGPRs total)
  auto loadA = [&](int k0, float4 v0[2], float4 v1[2]) {
    #pragma unroll
    for (int i = 0; i < 2; i++) {
      const int f = tid + 256 * i;
      const int kc = f & 3;
      const int kk = k0 + kc * 8;
      float4 a0 = make_float4(0.f, 0.f, 0.f, 0.f), a1 = a0;
      if (AMODE == 1) {
        const int tap = kk >> 10, din = kk & 1023;
        const int sin = asrow[i] + tap - 1;
        if (sin >= 0 && sin < Sq) {
          const float* p = A + ((long)(abat[i] * Sq + sin) * Dq + din);
          a0 = *(const float4*)p;
          a1 = *(const float4*)(p + 4);
        }
      } else {
        a0 = *(const float4*)(arp[i] + kk);
        a1 = *(const float4*)(arp[i] + kk + 4);
      }
      v0[i] = a0;
      v1[i] = a1;
    }
  };

  // B-step async stage into Bsx[buf] (no VGPR round-trip)
  auto issueB = [&](int k0, int buf) {
    const int kq0 = k0 >> 2;  // quad chunk index in Bx
    #pragma unroll
    for (int i = 0; i < 2; i++) {
      const int f = tid + 256 * i;
      const int kcb = f >> 7, n = f & 127;  // kcb uniform per wave; n lane-linear
      const u16* bp = Bx + ((long)(kq0 + 2 * kcb) * ldbN + n0 + n) * 8;
      GLL16(bp, &Bsx[buf][((2 * kcb) * 128 + n) * 8]);
      GLL16(bp + (long)ldbN * 8, &Bsx[buf][((2 * kcb + 1) * 128 + n) * 8]);
    }
  };

  // ---- prologue: step-0 A regs + step-0 B async stage ----
  float4 pv0[2], pv1[2];
  loadA(0, pv0, pv1);
  issueB(0, 0);

  int cur = 0;
  for (int k0 = 0; k0 < Ko; k0 += 32) {
    // ---- convert prefetched A regs -> Asx (axpk pairs) ----
    #pragma unroll
    for (int i = 0; i < 2; i++) {
      const int f = tid + 256 * i;
      const int m = f >> 2, kc = f & 3;
      uint4 wa, wb;
      wa.x = axpk(pv0[i].x);
      wa.y = axpk(pv0[i].y);
      wa.z = axpk(pv0[i].z);
      wa.w = axpk(pv0[i].w);
      wb.x = axpk(pv1[i].x);
      wb.y = axpk(pv1[i].y);
      wb.z = axpk(pv1[i].z);
      wb.w = axpk(pv1[i].w);
      *(uint4*)&Asx[((2 * kc) * 128 + m) * 8] = wa;
      *(uint4*)&Asx[((2 * kc + 1) * 128 + m) * 8] = wb;
    }
    __syncthreads();  // Asx visible; Bsx[cur] drained at prev tail barrier
    const bool more = (k0 + 32 < Ko);
    if (more) {
      loadA(k0 + 32, pv0, pv1);   // reg loads: latency hides under MFMAs
      issueB(k0 + 32, cur ^ 1);   // async LDS stage into other buffer
    }
    {
      const u16* Bc = Bsx[cur];
      f16x8 af[4], bf[4];
      // hh: lane-group q covers octet q = quads (2q, 2q+1)
      #pragma unroll
      for (int mf = 0; mf < 4; mf++)
        af[mf] = hi_octet(&Asx[((2 * q) * 128 + abase + mf * 16) * 8]);
      #pragma unroll
      for (int nf = 0; nf < 4; nf++)
        bf[nf] = lo_octet(&Bc[((2 * q) * 128 + bbase + nf * 16) * 8]);
      #pragma unroll
      for (int mf = 0; mf < 4; mf++)
        #pragma unroll
        for (int nf = 0; nf < 4; nf++)
          acch[mf][nf] = __builtin_amdgcn_mfma_f32_16x16x32_f16(
              af[mf], bf[nf], acch[mf][nf], 0, 0, 0);
      // cross: set s covers original k [s*16, s*16+16) = quads s*4+q per lane
      #pragma unroll
      for (int s = 0; s < 2; s++) {
        #pragma unroll
        for (int mf = 0; mf < 4; mf++)
          af[mf] =
              *(const f16x8*)&Asx[((s * 4 + q) * 128 + abase + mf * 16) * 8];
        #pragma unroll
        for (int nf = 0; nf < 4; nf++)
          bf[nf] =
              *(const f16x8*)&Bc[((s * 4 + q) * 128 + bbase + nf * 16) * 8];
        #pragma unroll
        for (int mf = 0; mf < 4; mf++)
          #pragma unroll
          for (int nf = 0; nf < 4; nf++)
            accx[mf][nf] = __builtin_amdgcn_mfma_f32_16x16x32_f16(
                af[mf], bf[nf], accx[mf][nf], 0, 0, 0);
      }
    }
    __syncthreads();  // drains next-step gll (+A reg loads) under MFMA cover
    cur ^= 1;
  }

  float bcol[4];
  #pragma unroll
  for (int nf = 0; nf < 4; nf++) bcol[nf] = bias[n0 + wc * 64 + nf * 16 + l16];
  #pragma unroll
  for (int mf = 0; mf < 4; mf++) {
    #pragma unroll
    for (int reg = 0; reg < 4; reg++) {
      const int row = wr * 64 + mf * 16 + q * 4 + reg;
      float* crow = C + (long)(m0 + row) * ldc;
      #pragma unroll
      for (int nf = 0; nf < 4; nf++) {
        const int col = n0 + wc * 64 + nf * 16 + l16;
        float v = acch[mf][nf][reg] + accx[mf][nf][reg] * (1.0f / 4096.0f) +
                  bcol[nf];
        if (EPI == 2) v += crow[col];
        crow[col] = v;
      }
    }
  }
}

// ===========================================================================
// BF16 MFMA GEMM (MoE only). 128x128 tile, BK=64. B staged via async
// global_load_lds into a DOUBLE-BUFFERED Bs (issued during MFMA phase).
// AMODE 5: A = fp32 x1 gathered via list, cvt->bf16 staging.
// AMODE 6: A = bf16 h rows (chunk-relative).
// EPI 1: bias+relu -> bf16 h.
// EPI 3: bias, weighted NON-ATOMIC accumulate into moe (exclusive per launch).
// ===========================================================================
template <int AMODE, int EPI>
__global__ __launch_bounds__(256) void gemm_b(
    const void* __restrict__ Av, const u16* __restrict__ Bmf,
    const float* __restrict__ bias, void* __restrict__ Cv,
    int K, int lda, int ldbN, int ldc,
    const int* __restrict__ list, const float* __restrict__ wslot,
    const int* __restrict__ offsp, const int* __restrict__ counts,
    float* __restrict__ moe, int eidx, int cbase) {
  __shared__ __align__(16) u16 As[8 * 128 * 8];
  __shared__ __align__(16) u16 Bs[2][8 * 128 * 8];

  const int tid = threadIdx.x;
  int sbx, sby;
  xcd_swz(sbx, sby);
  const int rel = cbase + sby * BM;
  const int cnt = counts[eidx];
  const int padded = ((cnt + 127) >> 7) << 7;
  if (rel >= padded) return;
  const int count_e = cnt;
  const int lr0 = rel;
  const int r0 = offsp[eidx] + rel;
  const int n0 = sbx * BN;
  const int mrow0 = sby * BM;

  const float* aptr[4];
  const u16* aptr6[4];
  bool aval[4];
  #pragma unroll
  for (int i = 0; i < 4; i++) {
    const int f = tid + 256 * i;
    const int m = f >> 3;  // 8 octets per row
    aval[i] = true;
    if (AMODE == 5) {
      const int lr = lr0 + m;
      aval[i] = (lr < count_e);
      const int tok = aval[i] ? list[r0 + m] : 0;
      aptr[i] = (const float*)Av + (long)tok * lda;
    } else {
      aptr6[i] = (const u16*)Av + (long)(mrow0 + m) * lda;
    }
  }

  f32x4 acc[4][4];
  #pragma unroll
  for (int i = 0; i < 4; i++)
    #pragma unroll
    for (int j = 0; j < 4; j++) acc[i][j] = (f32x4)(0.f);

  const int lane = tid & 63;
  const int wave = tid >> 6;
  const int wr = wave >> 1, wc = wave & 1;
  const int q = lane >> 4, l16 = lane & 15;

  auto issueB = [&](int k0, int buf) {
    const int kc0 = k0 >> 3;
    #pragma unroll
    for (int i = 0; i < 4; i++) {
      const int f = tid + 256 * i;
      const int kcb = f >> 7, n = f & 127;  // kcb uniform per wave; n lane-linear
      const u16* bp = Bmf + ((long)(kc0 + kcb) * ldbN + n0 + n) * 8;
      GLL16(bp, &Bs[buf][(kcb * 128 + n) * 8]);
    }
  };

  issueB(0, 0);
  int cur = 0;

  for (int k0 = 0; k0 < K; k0 += 64) {
    // ---- A staging (load + convert/copy + ds_write) ----
    #pragma unroll
    for (int i = 0; i < 4; i++) {
      const int f = tid + 256 * i;
      const int m = f >> 3, kc = f & 7;
      const int kk = k0 + kc * 8;
      uint4 w;
      if (AMODE == 6) {
        w = *(const uint4*)(aptr6[i] + kk);
      } else {
        float4 v0 = make_float4(0.f, 0.f, 0.f, 0.f), v1 = v0;
        if (aval[i]) {
          v0 = *(const float4*)(aptr[i] + kk);
          v1 = *(const float4*)(aptr[i] + kk + 4);
        }
        w.x = bfpk(v0.x, v0.y);
        w.y = bfpk(v0.z, v0.w);
        w.z = bfpk(v1.x, v1.y);
        w.w = bfpk(v1.z, v1.w);
      }
      *(uint4*)&As[(kc * 128 + m) * 8] = w;
    }
    __syncthreads();  // As visible; Bs[cur] drained at prev tail barrier
    if (k0 + 64 < K) issueB(k0 + 64, cur ^ 1);  // async, hides under MFMAs
    {
      const u16* Bc = Bs[cur];
      #pragma unroll
      for (int s = 0; s < 2; s++) {
        bf16x8 af[4], bfr[4];
        #pragma unroll
        for (int mf = 0; mf < 4; mf++)
          af[mf] = *(const bf16x8*)
              &As[((s * 4 + q) * 128 + wr * 64 + mf * 16 + l16) * 8];
        #pragma unroll
        for (int nf = 0; nf < 4; nf++)
          bfr[nf] = *(const bf16x8*)
              &Bc[((s * 4 + q) * 128 + wc * 64 + nf * 16 + l16) * 8];
        #pragma unroll
        for (int mf = 0; mf < 4; mf++)
          #pragma unroll
          for (int nf = 0; nf < 4; nf++)
            acc[mf][nf] = __builtin_amdgcn_mfma_f32_16x16x32_bf16(
                af[mf], bfr[nf], acc[mf][nf], 0, 0, 0);
      }
    }
    __syncthreads();  // drains next-step gll under MFMA cover
    cur ^= 1;
  }

  float bcol[4];
  #pragma unroll
  for (int nf = 0; nf < 4; nf++) bcol[nf] = bias[n0 + wc * 64 + nf * 16 + l16];
  #pragma unroll
  for (int mf = 0; mf < 4; mf++) {
    #pragma unroll
    for (int reg = 0; reg < 4; reg++) {
      const int row = wr * 64 + mf * 16 + q * 4 + reg;
      if (lr0 + row >= count_e) continue;
      int tok = 0;
      float wgt = 0.f;
      if (EPI == 3) {
        tok = list[r0 + row];
        wgt = wslot[r0 + row];
      }
      #pragma unroll
      for (int nf = 0; nf < 4; nf++) {
        float v = acc[mf][nf][reg] + bcol[nf];
        const int col = n0 + wc * 64 + nf * 16 + l16;
        if (EPI == 3) {
          float* mp = moe + (long)tok * Dq + col;
          *mp = *mp + wgt * v;   // non-atomic RMW: exclusive per launch
        } else {
          v = fmaxf(v, 0.f);
          ((u16*)Cv)[(long)(mrow0 + row) * ldc + col] = (u16)bf1(v);
        }
      }
    }
  }
}

// ---------------------------------------------------------------------------
// conv_w (D,D,3) -> split-pair layout [kc=768][1024][8], k = tap*1024 + din
// ---------------------------------------------------------------------------
__global__ __launch_bounds__(256) void wsplit_conv(const float* __restrict__ cw,
                                                   u16* __restrict__ dst) {
  const int n = blockIdx.x * 256 + threadIdx.x;  // dout
  const int kc = blockIdx.y;                     // 0..767
  uint4 w;
  u32* wp = (u32*)&w;
  #pragma unroll
  for (int j = 0; j < 4; j++) {
    const int k = kc * 4 + j;
    const int tap = k >> 10, din = k & 1023;
    wp[j] = bxpk(cw[(long)n * 3072 + din * 3 + tap]);
  }
  *(uint4*)(dst + ((long)kc * 1024 + n) * 8) = w;
}

// N x K fp32 row-major (W with x @ W.T semantics) -> split-pair [K/4][N][8]
__global__ __launch_bounds__(256) void wsplit_nk(const float* __restrict__ src,
                                                 u16* __restrict__ dst, int N,
                                                 int K) {
  const int n = blockIdx.x * 256 + threadIdx.x;
  const int kc = blockIdx.y;  // 0..K/4-1
  const float4 v = *(const float4*)(src + (long)n * K + kc * 4);
  uint4 w;
  w.x = bxpk(v.x);
  w.y = bxpk(v.y);
  w.z = bxpk(v.z);
  w.w = bxpk(v.w);
  *(uint4*)(dst + ((long)kc * N + n) * 8) = w;
}

// KxN fp32 (n contiguous) -> bf16 [kc][n][8]; grid (N/256, K/8)  (MoE weights)
__global__ __launch_bounds__(256) void kn2b_k(const float* __restrict__ src,
                                              u16* __restrict__ dst, int N) {
  const int n = blockIdx.x * 256 + threadIdx.x;
  const int kc = blockIdx.y;
  float v[8];
  #pragma unroll
  for (int j = 0; j < 8; j++) v[j] = src[(long)(kc * 8 + j) * N + n];
  uint4 w;
  w.x = bfpk(v[0], v[1]);
  w.y = bfpk(v[2], v[3]);
  w.z = bfpk(v[4], v[5]);
  w.w = bfpk(v[6], v[7]);
  *(uint4*)(dst + ((long)kc * N + n) * 8) = w;
}

// ---------------------------------------------------------------------------
// Attention on a seq chunk (fp32 qc): one wave per (n,h); lane = d.
// ---------------------------------------------------------------------------
__global__ __launch_bounds__(256) void attn_k(const float* __restrict__ qc,
                                              float* __restrict__ o, int nbase) {
  const int wid = blockIdx.x * 4 + (threadIdx.x >> 6);
  const int lane = threadIdx.x & 63;
  const int h = wid & 15;
  const int nl = wid >> 4;
  float q[4], k[4], v[4];
  #pragma unroll
  for (int l = 0; l < 4; l++) {
    const long base = (long)(l * QCN + nl) * 3072 + h * 64 + lane;
    q[l] = qc[base];
    k[l] = qc[base + Dq];
    v[l] = qc[base + 2 * Dq];
  }
  float sc[4][4];
  #pragma unroll
  for (int l = 0; l < 4; l++)
    #pragma unroll
    for (int m = 0; m < 4; m++) sc[l][m] = q[l] * k[m];
  #pragma unroll
  for (int off = 32; off >= 1; off >>= 1)
    #pragma unroll
    for (int l = 0; l < 4; l++)
      #pragma unroll
      for (int m = 0; m < 4; m++) sc[l][m] += __shfl_xor(sc[l][m], off, 64);
  float p[4][4];
  #pragma unroll
  for (int l = 0; l < 4; l++) {
    float s0[4], mx = -1e30f;
    #pragma unroll
    for (int m = 0; m < 4; m++) { s0[m] = sc[l][m] * 0.125f; mx = fmaxf(mx, s0[m]); }
    float sum = 0.f;
    #pragma unroll
    for (int m = 0; m < 4; m++) { p[l][m] = __expf(s0[m] - mx); sum += p[l][m]; }
    const float inv = 1.0f / sum;
    #pragma unroll
    for (int m = 0; m < 4; m++) p[l][m] *= inv;
  }
  #pragma unroll
  for (int l = 0; l < 4; l++) {
    float ov = 0.f;
    #pragma unroll
    for (int m = 0; m < 4; m++) ov = fmaf(p[l][m], v[m], ov);
    o[(long)(l * Sq + nbase + nl) * Dq + h * 64 + lane] = ov;
  }
}

// ---------------------------------------------------------------------------
// LayerNorm
// ---------------------------------------------------------------------------
__device__ __forceinline__ float block_sum256(float v, float* sbuf) {
  #pragma unroll
  for (int off = 32; off >= 1; off >>= 1) v += __shfl_xor(v, off, 64);
  const int w = threadIdx.x >> 6;
  __syncthreads();
  if ((threadIdx.x & 63) == 0) sbuf[w] = v;
  __syncthreads();
  return sbuf[0] + sbuf[1] + sbuf[2] + sbuf[3];
}

__device__ __forceinline__ void ln_core(const float xv[4], const float* g,
                                        const float* bb, float* outp, long base,
                                        float* sbuf) {
  const float tot = block_sum256(xv[0] + xv[1] + xv[2] + xv[3], sbuf);
  const float mean = tot * (1.0f / 1024.0f);
  const float d0 = xv[0] - mean, d1 = xv[1] - mean, d2 = xv[2] - mean,
              d3 = xv[3] - mean;
  const float var =
      block_sum256(d0 * d0 + d1 * d1 + d2 * d2 + d3 * d3, sbuf) * (1.0f / 1024.0f);
  const float inv = 1.0f / sqrtf(var + 1e-5f);
  const int c = threadIdx.x * 4;
  const float4 gg = *(const float4*)(g + c);
  const float4 bv = *(const float4*)(bb + c);
  float4 r;
  r.x = d0 * inv * gg.x + bv.x;
  r.y = d1 * inv * gg.y + bv.y;
  r.z = d2 * inv * gg.z + bv.z;
  r.w = d3 * inv * gg.w + bv.w;
  *(float4*)(outp + base) = r;
}

__global__ __launch_bounds__(256) void ln1_k(const float* __restrict__ xc,
                                             const float* __restrict__ g,
                                             const float* __restrict__ bb,
                                             float* __restrict__ outp) {
  __shared__ float sbuf[4];
  const long base = (long)blockIdx.x * Dq + threadIdx.x * 4;
  const float4 a = *(const float4*)(xc + base);
  const float xv[4] = {a.x, a.y, a.z, a.w};
  ln_core(xv, g, bb, outp, base, sbuf);
}

__global__ __launch_bounds__(256) void ln2_k(const float* __restrict__ x1,
                                             const float* __restrict__ moe,
                                             const float* __restrict__ g,
                                             const float* __restrict__ bb,
                                             float* __restrict__ outp) {
  __shared__ float sbuf[4];
  const long base = (long)blockIdx.x * Dq + threadIdx.x * 4;
  const float4 a = *(const float4*)(x1 + base);
  const float4 m = *(const float4*)(moe + base);
  const float xv[4] = {a.x + m.x, a.y + m.y, a.z + m.z, a.w + m.w};
  ln_core(xv, g, bb, outp, base, sbuf);
}

// ---------------------------------------------------------------------------
// MoE gating + compaction (fp32 x1 — selection bit-stable vs reference)
// ---------------------------------------------------------------------------
__global__ __launch_bounds__(256) void gate_k(const float* __restrict__ x1,
                                              const float* __restrict__ gw,
                                              const float* __restrict__ gb,
                                              int* __restrict__ e01,
                                              float* __restrict__ w01) {
  const int t = blockIdx.x * 4 + (threadIdx.x >> 6);
  const int lane = threadIdx.x & 63;
  const float* xr = x1 + (long)t * Dq;
  float acc[8];
  #pragma unroll
  for (int e = 0; e < 8; e++) acc[e] = 0.f;
  #pragma unroll
  for (int j = 0; j < 16; j++) {
    const int d = lane + 64 * j;
    const float xv = xr[d];
    const float4 g0 = *(const float4*)(gw + d * 8);
    const float4 g1 = *(const float4*)(gw + d * 8 + 4);
    acc[0] = fmaf(xv, g0.x, acc[0]);
    acc[1] = fmaf(xv, g0.y, acc[1]);
    acc[2] = fmaf(xv, g0.z, acc[2]);
    acc[3] = fmaf(xv, g0.w, acc[3]);
    acc[4] = fmaf(xv, g1.x, acc[4]);
    acc[5] = fmaf(xv, g1.y, acc[5]);
    acc[6] = fmaf(xv, g1.z, acc[6]);
    acc[7] = fmaf(xv, g1.w, acc[7]);
  }
  #pragma unroll
  for (int off = 32; off >= 1; off >>= 1)
    #pragma unroll
    for (int e = 0; e < 8; e++) acc[e] += __shfl_xor(acc[e], off, 64);
  if (lane == 0) {
    float mx = -1e30f;
    #pragma unroll
    for (int e = 0; e < 8; e++) { acc[e] += gb[e]; mx = fmaxf(mx, acc[e]); }
    float Z = 0.f, p[8];
    #pragma unroll
    for (int e = 0; e < 8; e++) { p[e] = __expf(acc[e] - mx); Z += p[e]; }
    const float invZ = 1.0f / Z;
    float b0 = -1.f, b1 = -1.f;
    int i0 = 0, i1 = 0;
    #pragma unroll
    for (int e = 0; e < 8; e++) {
      const float pe = p[e] * invZ;
      if (pe > b0) { b1 = b0; i1 = i0; b0 = pe; i0 = e; }
      else if (pe > b1) { b1 = pe; i1 = e; }
    }
    const float s = b0 + b1;
    e01[2 * t] = i0;
    e01[2 * t + 1] = i1;
    w01[2 * t] = b0 / s;
    w01[2 * t + 1] = b1 / s;
  }
}

__global__ void zero_k(int* p) {
  if (threadIdx.x < 16) p[threadIdx.x] = 0;
}

__global__ __launch_bounds__(256) void zerof_k(float* __restrict__ p) {
  const long i = ((long)blockIdx.x * 256 + threadIdx.x) * 4;
  *(float4*)(p + i) = make_float4(0.f, 0.f, 0.f, 0.f);
}

__global__ __launch_bounds__(256) void count_k(const int* __restrict__ e01,
                                               int* __restrict__ counts) {
  __shared__ int lc[8];
  const int tid = threadIdx.x;
  if (tid < 8) lc[tid] = 0;
  __syncthreads();
  const int t = blockIdx.x * 256 + tid;
  atomicAdd(&lc[e01[2 * t]], 1);
  atomicAdd(&lc[e01[2 * t + 1]], 1);
  __syncthreads();
  if (tid < 8) atomicAdd(&counts[tid], lc[tid]);
}

__global__ void offs_k(const int* __restrict__ counts, int* __restrict__ offsp) {
  if (threadIdx.x == 0) {
    int a = 0;
    for (int e = 0; e < 8; e++) {
      offsp[e] = a;
      a += ((counts[e] + 127) >> 7) << 7;
    }
    offsp[8] = a;
  }
}

__global__ __launch_bounds__(256) void scatter_k(
    const int* __restrict__ e01, const float* __restrict__ w01,
    int* __restrict__ cursor, const int* __restrict__ offsp,
    int* __restrict__ list, float* __restrict__ wslot) {
  __shared__ int lc[8];
  __shared__ int gbase[8];
  const int tid = threadIdx.x;
  if (tid < 8) lc[tid] = 0;
  __syncthreads();
  const int t = blockIdx.x * 256 + tid;
  const int e0 = e01[2 * t], e1 = e01[2 * t + 1];
  const int p0 = atomicAdd(&lc[e0], 1);
  const int p1 = atomicAdd(&lc[e1], 1);
  __syncthreads();
  if (tid < 8) gbase[tid] = atomicAdd(&cursor[tid], lc[tid]);
  __syncthreads();
  const int s0 = offsp[e0] + gbase[e0] + p0;
  const int s1 = offsp[e1] + gbase[e1] + p1;
  list[s0] = t;
  list[s1] = t;
  wslot[s0] = w01[2 * t];
  wslot[s1] = w01[2 * t + 1];
}

// ---------------------------------------------------------------------------
extern "C" void kernel_launch(void* const* d_in, const int* in_sizes, int n_in,
                              void* d_out, int out_size, void* d_ws,
                              size_t ws_size, hipStream_t stream) {
  const float* x          = (const float*)d_in[0];
  const float* conv_w     = (const float*)d_in[1];
  const float* conv_b     = (const float*)d_in[2];
  const float* in_proj_w  = (const float*)d_in[3];
  const float* in_proj_b  = (const float*)d_in[4];
  const float* out_proj_w = (const float*)d_in[5];
  const float* out_proj_b = (const float*)d_in[6];
  const float* ln1_g      = (const float*)d_in[7];
  const float* ln1_b      = (const float*)d_in[8];
  const float* gate_w     = (const float*)d_in[9];
  const float* gate_b     = (const float*)d_in[10];
  const float* w1         = (const float*)d_in[11];
  const float* b1         = (const float*)d_in[12];
  const float* w2         = (const float*)d_in[13];
  const float* b2         = (const float*)d_in[14];
  const float* ln2_g      = (const float*)d_in[15];
  const float* ln2_b      = (const float*)d_in[16];

  float* ws = (float*)d_ws;
  char* wsb = (char*)d_ws;
  int* si      = (int*)ws;
  int* counts  = si;
  int* cursor  = si + 8;
  int* offsp   = si + 16;
  int* e01     = si + 32;
  float* w01   = (float*)(si + 32 + 2 * Tq);
  int* list    = si + 32 + 4 * Tq;
  float* wslot = (float*)(list + PADT);

  float* xc   = ws + OFF_XC;      // conv out (A) / moe accumulator (B)
  float* moe  = ws + OFF_XC;
  float* qc   = ws + OFF_Q;       // qkv chunk fp32 (A)
  u16* wtx    = (u16*)(ws + OFF_WT);   // split-pair f16 weights (A), reused
  u16* h      = (u16*)(wsb + H_B);     // MoE hidden bf16 (B)
  u16* w1be   = (u16*)(wsb + W1E_B);   // per-expert bf16 weights (B)
  u16* w2be   = (u16*)(wsb + W2E_B);
  float* o    = (float*)d_out;    // attn out -> x1 -> final out
  float* x1   = (float*)d_out;
  float* out  = (float*)d_out;

  zero_k<<<1, 64, 0, stream>>>(counts);
  // conv weight -> split-pair f16 [768][1024][8]
  wsplit_conv<<<dim3(4, 768), 256, 0, stream>>>(conv_w, wtx);
  // conv as GEMM (fp32-accuracy f16 split): xc = shift(x) @ wt + conv_b
  gemm_h<1, 0><<<dim3(Dq / BN, Tq / BM), 256, 0, stream>>>(
      x, wtx, conv_b, xc, 3 * Dq, Dq, Dq, Dq, 0);
  // in_proj weight -> split-pair [256][3072][8]
  wsplit_nk<<<dim3(12, 256), 256, 0, stream>>>(in_proj_w, wtx, 3 * Dq, Dq);
  // qkv + attention, 4 seq chunks of 1024
  for (int c = 0; c < Sq / QCN; c++) {
    gemm_h<4, 0><<<dim3(3 * Dq / BN, QROWS / BM), 256, 0, stream>>>(
        xc, wtx, in_proj_b, qc, Dq, Dq, 3 * Dq, 3 * Dq, c * QCN);
    attn_k<<<(QCN * Hq) / 4, 256, 0, stream>>>(qc, o, c * QCN);
  }
  // out_proj weight -> split-pair [256][1024][8]
  wsplit_nk<<<dim3(4, 256), 256, 0, stream>>>(out_proj_w, wtx, Dq, Dq);
  // attn-out projection accumulated into xc
  gemm_h<0, 2><<<dim3(Dq / BN, Tq / BM), 256, 0, stream>>>(
      o, wtx, out_proj_b, xc, Dq, Dq, Dq, Dq, 0);
  // x1 = LN1(xc) into d_out
  ln1_k<<<Tq, 256, 0, stream>>>(xc, ln1_g, ln1_b, x1);
  // moe accumulator = 0 (overlays dead xc)
  zerof_k<<<Tq, 256, 0, stream>>>(moe);
  // gating + compaction (fp32 x1 — selection bit-stable vs reference)
  gate_k<<<Tq / 4, 256, 0, stream>>>(x1, gate_w, gate_b, e01, w01);
  count_k<<<Tq / 256, 256, 0, stream>>>(e01, counts);
  offs_k<<<1, 64, 0, stream>>>(counts, offsp);
  scatter_k<<<Tq / 256, 256, 0, stream>>>(e01, w01, cursor, offsp, list, wslot);
  // MoE: per-expert bf16 weight streaming + MFMA GEMMs
  for (int e = 0; e < Eq; e++) {
    kn2b_k<<<dim3(HIDq / 256, Dq / 8), 256, 0, stream>>>(
        w1 + (long)e * Dq * HIDq, w1be, HIDq);
    kn2b_k<<<dim3(Dq / 256, HIDq / 8), 256, 0, stream>>>(
        w2 + (long)e * HIDq * Dq, w2be, Dq);
    for (int c = 0; c < MAXC; c++) {
      gemm_b<5, 1><<<dim3(HIDq / BN, ECH / BM), 256, 0, stream>>>(
          x1, w1be, b1 + (long)e * HIDq, h, Dq, Dq, HIDq, HIDq,
          list, wslot, offsp, counts, nullptr, e, c * ECH);
      gemm_b<6, 3><<<dim3(Dq / BN, ECH / BM), 256, 0, stream>>>(
          h, w2be, b2 + (long)e * Dq, nullptr, HIDq, HIDq, Dq, Dq,
          list, wslot, offsp, counts, moe, e, c * ECH);
    }
  }
  // out = LN2(x1 + moe)
  ln2_k<<<Tq, 256, 0, stream>>>(x1, moe, ln2_g, ln2_b, out);
}

// Round 11
// 3635.078 us; speedup vs baseline: 1.1583x; 1.1583x over previous
//
#include <hip/hip_runtime.h>

typedef unsigned short u16;
typedef unsigned int u32;
typedef __attribute__((ext_vector_type(8))) short bf16x8;
typedef __attribute__((ext_vector_type(8))) _Float16 f16x8;
typedef __attribute__((ext_vector_type(4))) float f32x4;

// ---------------------------------------------------------------------------
// Problem constants
// ---------------------------------------------------------------------------
constexpr int Bq = 4, Sq = 4096, Dq = 1024, Hq = 16, Eq = 8, HIDq = 4096;
constexpr int Tq = Bq * Sq;               // 16384 tokens
constexpr long TD = (long)Tq * Dq;        // 16,777,216
constexpr int PADT = 33792;               // padded MoE slots cap
constexpr int QCN  = 1024;                // seq chunk for qkv/attn
constexpr int QROWS = 4 * QCN;
constexpr int ECH  = 4096;                // MoE expert-chunk rows
constexpr int MAXC = 3;                   // chunks per expert (cap 12288)

// ---------------------------------------------------------------------------
// Workspace layout (unchanged, proven safe).
// ---------------------------------------------------------------------------
constexpr long OFF_XC = 262144;                        // floats
constexpr long OFF_Q  = OFF_XC + TD;                   // floats
constexpr long OFF_WT = OFF_Q + (long)QROWS * 3 * Dq;  // floats
constexpr long H_B    = OFF_Q * 4;                     // bytes
constexpr long W1E_B  = H_B + (long)2 * ECH * HIDq;    // +33,554,432
constexpr long W2E_B  = W1E_B + (long)2 * Dq * HIDq;   // +8,388,608

// ---------------------------------------------------------------------------
// bf16 helpers (RNE)
// ---------------------------------------------------------------------------
__device__ __forceinline__ u32 bf1(float x) {
  u32 u = __builtin_bit_cast(u32, x);
  return (u + 0x7fffu + ((u >> 16) & 1u)) >> 16;
}
__device__ __forceinline__ u32 bfpk(float lo, float hi) {
  return bf1(lo) | (bf1(hi) << 16);
}

// ---------------------------------------------------------------------------
// f16 split helpers: a = ah + al*2^-12; al stored pre-scaled by 2^12.
// ---------------------------------------------------------------------------
__device__ __forceinline__ u16 f16b(float v) {
  _Float16 h = (_Float16)v;
  return __builtin_bit_cast(u16, h);
}
// A-side cross pair: [al_s | ah<<16]
__device__ __forceinline__ u32 axpk(float v) {
  _Float16 h = (_Float16)v;
  float hf = (float)h;
  u16 l = f16b((v - hf) * 4096.0f);
  return (u32)l | ((u32)__builtin_bit_cast(u16, h) << 16);
}
// B-side stored pair: [bh | bl_s<<16]
__device__ __forceinline__ u32 bxpk(float v) {
  _Float16 h = (_Float16)v;
  float hf = (float)h;
  u16 l = f16b((v - hf) * 4096.0f);
  return (u32)__builtin_bit_cast(u16, h) | ((u32)l << 16);
}

#define BM 128
#define BN 128

// async global->LDS, 16B per lane (dest = wave-uniform base + lane*16)
#define GLL16(SRC, DST)                                                \
  __builtin_amdgcn_global_load_lds(                                    \
      (const __attribute__((address_space(1))) void*)(SRC),            \
      (__attribute__((address_space(3))) void*)(DST), 16, 0, 0)

// ---------------------------------------------------------------------------
// XCD-aware block swizzle (kept: FETCH 807->230 MB measured R9).
// ---------------------------------------------------------------------------
__device__ __forceinline__ void xcd_swz(int& bx, int& by) {
  const int nbx = (int)gridDim.x;
  const int nwg = nbx * (int)gridDim.y;
  int bid = (int)blockIdx.y * nbx + (int)blockIdx.x;
  bid = (bid & 7) * (nwg >> 3) + (bid >> 3);
  bx = bid % nbx;
  by = bid / nbx;
}

// ---------------------------------------------------------------------------
// Octet extraction from split-pair quads in LDS.
// ---------------------------------------------------------------------------
__device__ __forceinline__ f16x8 hi_octet(const u16* p) {
  const uint4 a = *(const uint4*)p;
  const uint4 b = *(const uint4*)(p + 1024);  // next quad-row block
  uint4 r;
  r.x = __builtin_amdgcn_perm(a.y, a.x, 0x07060302u);
  r.y = __builtin_amdgcn_perm(a.w, a.z, 0x07060302u);
  r.z = __builtin_amdgcn_perm(b.y, b.x, 0x07060302u);
  r.w = __builtin_amdgcn_perm(b.w, b.z, 0x07060302u);
  return __builtin_bit_cast(f16x8, r);
}
__device__ __forceinline__ f16x8 lo_octet(const u16* p) {
  const uint4 a = *(const uint4*)p;
  const uint4 b = *(const uint4*)(p + 1024);
  uint4 r;
  r.x = __builtin_amdgcn_perm(a.y, a.x, 0x05040100u);
  r.y = __builtin_amdgcn_perm(a.w, a.z, 0x05040100u);
  r.z = __builtin_amdgcn_perm(b.y, b.x, 0x05040100u);
  r.w = __builtin_amdgcn_perm(b.w, b.z, 0x05040100u);
  return __builtin_bit_cast(f16x8, r);
}

// ===========================================================================
// f16 split-precision MFMA GEMM, SINGLE-PASS + SOFTWARE-PIPELINED STAGING
// (R10-measured: 487 -> 439 us/dispatch, kept unchanged):
//   - A prefetched into registers one step ahead.
//   - B staged via async global_load_lds into a DOUBLE-BUFFERED Bsx.
// Numerics bit-identical to R5's verified kernel.
// AMODE: 0 direct rows | 1 conv-gather from x | 4 qkv-chunk gather from xc
// EPI:   0 bias store | 2 bias + C_old accumulate store
// ===========================================================================
template <int AMODE, int EPI>
__global__ __launch_bounds__(256, 2) void gemm_h(
    const float* __restrict__ A, const u16* __restrict__ Bx,
    const float* __restrict__ bias, float* __restrict__ C,
    int Ko, int lda, int ldbN, int ldc, int nbase) {
  // quad-granular layouts: [quad 0..7][row 0..127][8 u16 = 4 pairs]
  __shared__ __align__(16) u16 Asx[8 * 128 * 8];
  __shared__ __align__(16) u16 Bsx[2][8 * 128 * 8];

  const int tid = threadIdx.x;
  int sbx, sby;
  xcd_swz(sbx, sby);
  const int m0 = sby * BM;
  const int n0 = sbx * BN;

  const float* arp[2];
  int abat[2], asrow[2];
  #pragma unroll
  for (int i = 0; i < 2; i++) {
    const int f = tid + 256 * i;
    const int m = f >> 2;
    if (AMODE == 0) {
      arp[i] = A + (long)(m0 + m) * lda;
    } else if (AMODE == 1) {
      abat[i] = (m0 + m) >> 12;
      asrow[i] = (m0 + m) & 4095;
    } else {  // AMODE == 4
      const int mm = m0 + m;
      const int l = mm >> 10;
      const int n = nbase + (mm & 1023);
      arp[i] = A + (long)(l * Sq + n) * lda;
    }
  }

  f32x4 acch[4][4], accx[4][4];
  #pragma unroll
  for (int i = 0; i < 4; i++)
    #pragma unroll
    for (int j = 0; j < 4; j++) {
      acch[i][j] = (f32x4)(0.f);
      accx[i][j] = (f32x4)(0.f);
    }

  const int lane = tid & 63;
  const int wave = tid >> 6;
  const int wr = wave >> 1, wc = wave & 1;
  const int q = lane >> 4, l16 = lane & 15;
  const int abase = wr * 64 + l16;
  const int bbase = wc * 64 + l16;

  // A-step load into registers (8 fp32 per thread-iter, 16 VGPRs total)
  auto loadA = [&](int k0, float4 v0[2], float4 v1[2]) {
    #pragma unroll
    for (int i = 0; i < 2; i++) {
      const int f = tid + 256 * i;
      const int kc = f & 3;
      const int kk = k0 + kc * 8;
      float4 a0 = make_float4(0.f, 0.f, 0.f, 0.f), a1 = a0;
      if (AMODE == 1) {
        const int tap = kk >> 10, din = kk & 1023;
        const int sin = asrow[i] + tap - 1;
        if (sin >= 0 && sin < Sq) {
          const float* p = A + ((long)(abat[i] * Sq + sin) * Dq + din);
          a0 = *(const float4*)p;
          a1 = *(const float4*)(p + 4);
        }
      } else {
        a0 = *(const float4*)(arp[i] + kk);
        a1 = *(const float4*)(arp[i] + kk + 4);
      }
      v0[i] = a0;
      v1[i] = a1;
    }
  };

  // B-step async stage into Bsx[buf] (no VGPR round-trip)
  auto issueB = [&](int k0, int buf) {
    const int kq0 = k0 >> 2;  // quad chunk index in Bx
    #pragma unroll
    for (int i = 0; i < 2; i++) {
      const int f = tid + 256 * i;
      const int kcb = f >> 7, n = f & 127;  // kcb uniform per wave; n lane-linear
      const u16* bp = Bx + ((long)(kq0 + 2 * kcb) * ldbN + n0 + n) * 8;
      GLL16(bp, &Bsx[buf][((2 * kcb) * 128 + n) * 8]);
      GLL16(bp + (long)ldbN * 8, &Bsx[buf][((2 * kcb + 1) * 128 + n) * 8]);
    }
  };

  // ---- prologue: step-0 A regs + step-0 B async stage ----
  float4 pv0[2], pv1[2];
  loadA(0, pv0, pv1);
  issueB(0, 0);

  int cur = 0;
  for (int k0 = 0; k0 < Ko; k0 += 32) {
    // ---- convert prefetched A regs -> Asx (axpk pairs) ----
    #pragma unroll
    for (int i = 0; i < 2; i++) {
      const int f = tid + 256 * i;
      const int m = f >> 2, kc = f & 3;
      uint4 wa, wb;
      wa.x = axpk(pv0[i].x);
      wa.y = axpk(pv0[i].y);
      wa.z = axpk(pv0[i].z);
      wa.w = axpk(pv0[i].w);
      wb.x = axpk(pv1[i].x);
      wb.y = axpk(pv1[i].y);
      wb.z = axpk(pv1[i].z);
      wb.w = axpk(pv1[i].w);
      *(uint4*)&Asx[((2 * kc) * 128 + m) * 8] = wa;
      *(uint4*)&Asx[((2 * kc + 1) * 128 + m) * 8] = wb;
    }
    __syncthreads();  // Asx visible; Bsx[cur] drained at prev tail barrier
    const bool more = (k0 + 32 < Ko);
    if (more) {
      loadA(k0 + 32, pv0, pv1);   // reg loads: latency hides under MFMAs
      issueB(k0 + 32, cur ^ 1);   // async LDS stage into other buffer
    }
    {
      const u16* Bc = Bsx[cur];
      f16x8 af[4], bf[4];
      // hh: lane-group q covers octet q = quads (2q, 2q+1)
      #pragma unroll
      for (int mf = 0; mf < 4; mf++)
        af[mf] = hi_octet(&Asx[((2 * q) * 128 + abase + mf * 16) * 8]);
      #pragma unroll
      for (int nf = 0; nf < 4; nf++)
        bf[nf] = lo_octet(&Bc[((2 * q) * 128 + bbase + nf * 16) * 8]);
      #pragma unroll
      for (int mf = 0; mf < 4; mf++)
        #pragma unroll
        for (int nf = 0; nf < 4; nf++)
          acch[mf][nf] = __builtin_amdgcn_mfma_f32_16x16x32_f16(
              af[mf], bf[nf], acch[mf][nf], 0, 0, 0);
      // cross: set s covers original k [s*16, s*16+16) = quads s*4+q per lane
      #pragma unroll
      for (int s = 0; s < 2; s++) {
        #pragma unroll
        for (int mf = 0; mf < 4; mf++)
          af[mf] =
              *(const f16x8*)&Asx[((s * 4 + q) * 128 + abase + mf * 16) * 8];
        #pragma unroll
        for (int nf = 0; nf < 4; nf++)
          bf[nf] =
              *(const f16x8*)&Bc[((s * 4 + q) * 128 + bbase + nf * 16) * 8];
        #pragma unroll
        for (int mf = 0; mf < 4; mf++)
          #pragma unroll
          for (int nf = 0; nf < 4; nf++)
            accx[mf][nf] = __builtin_amdgcn_mfma_f32_16x16x32_f16(
                af[mf], bf[nf], accx[mf][nf], 0, 0, 0);
      }
    }
    __syncthreads();  // drains next-step gll (+A reg loads) under MFMA cover
    cur ^= 1;
  }

  float bcol[4];
  #pragma unroll
  for (int nf = 0; nf < 4; nf++) bcol[nf] = bias[n0 + wc * 64 + nf * 16 + l16];
  #pragma unroll
  for (int mf = 0; mf < 4; mf++) {
    #pragma unroll
    for (int reg = 0; reg < 4; reg++) {
      const int row = wr * 64 + mf * 16 + q * 4 + reg;
      float* crow = C + (long)(m0 + row) * ldc;
      #pragma unroll
      for (int nf = 0; nf < 4; nf++) {
        const int col = n0 + wc * 64 + nf * 16 + l16;
        float v = acch[mf][nf][reg] + accx[mf][nf][reg] * (1.0f / 4096.0f) +
                  bcol[nf];
        if (EPI == 2) v += crow[col];
        crow[col] = v;
      }
    }
  }
}

// ===========================================================================
// BF16 MFMA GEMM (MoE only) — REVERTED to the R9-measured version.
// R10's gll+double-buffer variant (48 KB LDS) cut occupancy 5->3 blocks/CU
// and cost ~850 us across the MoE span: gemm_b depends on multi-block TLP
// to hide its gather-A staging, not on in-loop pipelining.
// 128x128 tile, BK=64 (32 MFMAs per barrier-pair), 32 KB LDS.
// AMODE 5: A = fp32 x1 gathered via list, cvt->bf16 staging.
// AMODE 6: A = bf16 h rows (chunk-relative).
// EPI 1: bias+relu -> bf16 h.
// EPI 3: bias, weighted NON-ATOMIC accumulate into moe (exclusive per launch).
// ===========================================================================
template <int AMODE, int EPI>
__global__ __launch_bounds__(256) void gemm_b(
    const void* __restrict__ Av, const u16* __restrict__ Bmf,
    const float* __restrict__ bias, void* __restrict__ Cv,
    int K, int lda, int ldbN, int ldc,
    const int* __restrict__ list, const float* __restrict__ wslot,
    const int* __restrict__ offsp, const int* __restrict__ counts,
    float* __restrict__ moe, int eidx, int cbase) {
  __shared__ __align__(16) u16 As[8 * 128 * 8];
  __shared__ __align__(16) u16 Bs[8 * 128 * 8];

  const int tid = threadIdx.x;
  int sbx, sby;
  xcd_swz(sbx, sby);
  const int rel = cbase + sby * BM;
  const int cnt = counts[eidx];
  const int padded = ((cnt + 127) >> 7) << 7;
  if (rel >= padded) return;
  const int count_e = cnt;
  const int lr0 = rel;
  const int r0 = offsp[eidx] + rel;
  const int n0 = sbx * BN;
  const int mrow0 = sby * BM;

  const float* aptr[4];
  const u16* aptr6[4];
  bool aval[4];
  #pragma unroll
  for (int i = 0; i < 4; i++) {
    const int f = tid + 256 * i;
    const int m = f >> 3;  // 8 octets per row
    aval[i] = true;
    if (AMODE == 5) {
      const int lr = lr0 + m;
      aval[i] = (lr < count_e);
      const int tok = aval[i] ? list[r0 + m] : 0;
      aptr[i] = (const float*)Av + (long)tok * lda;
    } else {
      aptr6[i] = (const u16*)Av + (long)(mrow0 + m) * lda;
    }
  }

  f32x4 acc[4][4];
  #pragma unroll
  for (int i = 0; i < 4; i++)
    #pragma unroll
    for (int j = 0; j < 4; j++) acc[i][j] = (f32x4)(0.f);

  const int lane = tid & 63;
  const int wave = tid >> 6;
  const int wr = wave >> 1, wc = wave & 1;
  const int q = lane >> 4, l16 = lane & 15;

  for (int k0 = 0; k0 < K; k0 += 64) {
    #pragma unroll
    for (int i = 0; i < 4; i++) {
      const int f = tid + 256 * i;
      const int m = f >> 3, kc = f & 7;
      const int kk = k0 + kc * 8;
      uint4 w;
      if (AMODE == 6) {
        w = *(const uint4*)(aptr6[i] + kk);
      } else {
        float4 v0 = make_float4(0.f, 0.f, 0.f, 0.f), v1 = v0;
        if (aval[i]) {
          v0 = *(const float4*)(aptr[i] + kk);
          v1 = *(const float4*)(aptr[i] + kk + 4);
        }
        w.x = bfpk(v0.x, v0.y);
        w.y = bfpk(v0.z, v0.w);
        w.z = bfpk(v1.x, v1.y);
        w.w = bfpk(v1.z, v1.w);
      }
      *(uint4*)&As[(kc * 128 + m) * 8] = w;
    }
    const int kc0 = k0 >> 3;
    #pragma unroll
    for (int i = 0; i < 4; i++) {
      const int f = tid + 256 * i;
      const int kcb = f >> 7, n = f & 127;
      const uint4 wb =
          *(const uint4*)(Bmf + ((long)(kc0 + kcb) * ldbN + n0 + n) * 8);
      *(uint4*)&Bs[(kcb * 128 + n) * 8] = wb;
    }
    __syncthreads();
    #pragma unroll
    for (int s = 0; s < 2; s++) {
      bf16x8 af[4], bfr[4];
      #pragma unroll
      for (int mf = 0; mf < 4; mf++)
        af[mf] = *(const bf16x8*)
            &As[((s * 4 + q) * 128 + wr * 64 + mf * 16 + l16) * 8];
      #pragma unroll
      for (int nf = 0; nf < 4; nf++)
        bfr[nf] = *(const bf16x8*)
            &Bs[((s * 4 + q) * 128 + wc * 64 + nf * 16 + l16) * 8];
      #pragma unroll
      for (int mf = 0; mf < 4; mf++)
        #pragma unroll
        for (int nf = 0; nf < 4; nf++)
          acc[mf][nf] = __builtin_amdgcn_mfma_f32_16x16x32_bf16(
              af[mf], bfr[nf], acc[mf][nf], 0, 0, 0);
    }
    __syncthreads();
  }

  float bcol[4];
  #pragma unroll
  for (int nf = 0; nf < 4; nf++) bcol[nf] = bias[n0 + wc * 64 + nf * 16 + l16];
  #pragma unroll
  for (int mf = 0; mf < 4; mf++) {
    #pragma unroll
    for (int reg = 0; reg < 4; reg++) {
      const int row = wr * 64 + mf * 16 + q * 4 + reg;
      if (lr0 + row >= count_e) continue;
      int tok = 0;
      float wgt = 0.f;
      if (EPI == 3) {
        tok = list[r0 + row];
        wgt = wslot[r0 + row];
      }
      #pragma unroll
      for (int nf = 0; nf < 4; nf++) {
        float v = acc[mf][nf][reg] + bcol[nf];
        const int col = n0 + wc * 64 + nf * 16 + l16;
        if (EPI == 3) {
          float* mp = moe + (long)tok * Dq + col;
          *mp = *mp + wgt * v;   // non-atomic RMW: exclusive per launch
        } else {
          v = fmaxf(v, 0.f);
          ((u16*)Cv)[(long)(mrow0 + row) * ldc + col] = (u16)bf1(v);
        }
      }
    }
  }
}

// ---------------------------------------------------------------------------
// conv_w (D,D,3) -> split-pair layout [kc=768][1024][8], k = tap*1024 + din
// ---------------------------------------------------------------------------
__global__ __launch_bounds__(256) void wsplit_conv(const float* __restrict__ cw,
                                                   u16* __restrict__ dst) {
  const int n = blockIdx.x * 256 + threadIdx.x;  // dout
  const int kc = blockIdx.y;                     // 0..767
  uint4 w;
  u32* wp = (u32*)&w;
  #pragma unroll
  for (int j = 0; j < 4; j++) {
    const int k = kc * 4 + j;
    const int tap = k >> 10, din = k & 1023;
    wp[j] = bxpk(cw[(long)n * 3072 + din * 3 + tap]);
  }
  *(uint4*)(dst + ((long)kc * 1024 + n) * 8) = w;
}

// N x K fp32 row-major (W with x @ W.T semantics) -> split-pair [K/4][N][8]
__global__ __launch_bounds__(256) void wsplit_nk(const float* __restrict__ src,
                                                 u16* __restrict__ dst, int N,
                                                 int K) {
  const int n = blockIdx.x * 256 + threadIdx.x;
  const int kc = blockIdx.y;  // 0..K/4-1
  const float4 v = *(const float4*)(src + (long)n * K + kc * 4);
  uint4 w;
  w.x = bxpk(v.x);
  w.y = bxpk(v.y);
  w.z = bxpk(v.z);
  w.w = bxpk(v.w);
  *(uint4*)(dst + ((long)kc * N + n) * 8) = w;
}

// KxN fp32 (n contiguous) -> bf16 [kc][n][8]; grid (N/256, K/8)  (MoE weights)
__global__ __launch_bounds__(256) void kn2b_k(const float* __restrict__ src,
                                              u16* __restrict__ dst, int N) {
  const int n = blockIdx.x * 256 + threadIdx.x;
  const int kc = blockIdx.y;
  float v[8];
  #pragma unroll
  for (int j = 0; j < 8; j++) v[j] = src[(long)(kc * 8 + j) * N + n];
  uint4 w;
  w.x = bfpk(v[0], v[1]);
  w.y = bfpk(v[2], v[3]);
  w.z = bfpk(v[4], v[5]);
  w.w = bfpk(v[6], v[7]);
  *(uint4*)(dst + ((long)kc * N + n) * 8) = w;
}

// ---------------------------------------------------------------------------
// Attention on a seq chunk (fp32 qc): one wave per (n,h); lane = d.
// ---------------------------------------------------------------------------
__global__ __launch_bounds__(256) void attn_k(const float* __restrict__ qc,
                                              float* __restrict__ o, int nbase) {
  const int wid = blockIdx.x * 4 + (threadIdx.x >> 6);
  const int lane = threadIdx.x & 63;
  const int h = wid & 15;
  const int nl = wid >> 4;
  float q[4], k[4], v[4];
  #pragma unroll
  for (int l = 0; l < 4; l++) {
    const long base = (long)(l * QCN + nl) * 3072 + h * 64 + lane;
    q[l] = qc[base];
    k[l] = qc[base + Dq];
    v[l] = qc[base + 2 * Dq];
  }
  float sc[4][4];
  #pragma unroll
  for (int l = 0; l < 4; l++)
    #pragma unroll
    for (int m = 0; m < 4; m++) sc[l][m] = q[l] * k[m];
  #pragma unroll
  for (int off = 32; off >= 1; off >>= 1)
    #pragma unroll
    for (int l = 0; l < 4; l++)
      #pragma unroll
      for (int m = 0; m < 4; m++) sc[l][m] += __shfl_xor(sc[l][m], off, 64);
  float p[4][4];
  #pragma unroll
  for (int l = 0; l < 4; l++) {
    float s0[4], mx = -1e30f;
    #pragma unroll
    for (int m = 0; m < 4; m++) { s0[m] = sc[l][m] * 0.125f; mx = fmaxf(mx, s0[m]); }
    float sum = 0.f;
    #pragma unroll
    for (int m = 0; m < 4; m++) { p[l][m] = __expf(s0[m] - mx); sum += p[l][m]; }
    const float inv = 1.0f / sum;
    #pragma unroll
    for (int m = 0; m < 4; m++) p[l][m] *= inv;
  }
  #pragma unroll
  for (int l = 0; l < 4; l++) {
    float ov = 0.f;
    #pragma unroll
    for (int m = 0; m < 4; m++) ov = fmaf(p[l][m], v[m], ov);
    o[(long)(l * Sq + nbase + nl) * Dq + h * 64 + lane] = ov;
  }
}

// ---------------------------------------------------------------------------
// LayerNorm
// ---------------------------------------------------------------------------
__device__ __forceinline__ float block_sum256(float v, float* sbuf) {
  #pragma unroll
  for (int off = 32; off >= 1; off >>= 1) v += __shfl_xor(v, off, 64);
  const int w = threadIdx.x >> 6;
  __syncthreads();
  if ((threadIdx.x & 63) == 0) sbuf[w] = v;
  __syncthreads();
  return sbuf[0] + sbuf[1] + sbuf[2] + sbuf[3];
}

__device__ __forceinline__ void ln_core(const float xv[4], const float* g,
                                        const float* bb, float* outp, long base,
                                        float* sbuf) {
  const float tot = block_sum256(xv[0] + xv[1] + xv[2] + xv[3], sbuf);
  const float mean = tot * (1.0f / 1024.0f);
  const float d0 = xv[0] - mean, d1 = xv[1] - mean, d2 = xv[2] - mean,
              d3 = xv[3] - mean;
  const float var =
      block_sum256(d0 * d0 + d1 * d1 + d2 * d2 + d3 * d3, sbuf) * (1.0f / 1024.0f);
  const float inv = 1.0f / sqrtf(var + 1e-5f);
  const int c = threadIdx.x * 4;
  const float4 gg = *(const float4*)(g + c);
  const float4 bv = *(const float4*)(bb + c);
  float4 r;
  r.x = d0 * inv * gg.x + bv.x;
  r.y = d1 * inv * gg.y + bv.y;
  r.z = d2 * inv * gg.z + bv.z;
  r.w = d3 * inv * gg.w + bv.w;
  *(float4*)(outp + base) = r;
}

__global__ __launch_bounds__(256) void ln1_k(const float* __restrict__ xc,
                                             const float* __restrict__ g,
                                             const float* __restrict__ bb,
                                             float* __restrict__ outp) {
  __shared__ float sbuf[4];
  const long base = (long)blockIdx.x * Dq + threadIdx.x * 4;
  const float4 a = *(const float4*)(xc + base);
  const float xv[4] = {a.x, a.y, a.z, a.w};
  ln_core(xv, g, bb, outp, base, sbuf);
}

__global__ __launch_bounds__(256) void ln2_k(const float* __restrict__ x1,
                                             const float* __restrict__ moe,
                                             const float* __restrict__ g,
                                             const float* __restrict__ bb,
                                             float* __restrict__ outp) {
  __shared__ float sbuf[4];
  const long base = (long)blockIdx.x * Dq + threadIdx.x * 4;
  const float4 a = *(const float4*)(x1 + base);
  const float4 m = *(const float4*)(moe + base);
  const float xv[4] = {a.x + m.x, a.y + m.y, a.z + m.z, a.w + m.w};
  ln_core(xv, g, bb, outp, base, sbuf);
}

// ---------------------------------------------------------------------------
// MoE gating + compaction (fp32 x1 — selection bit-stable vs reference)
// ---------------------------------------------------------------------------
__global__ __launch_bounds__(256) void gate_k(const float* __restrict__ x1,
                                              const float* __restrict__ gw,
                                              const float* __restrict__ gb,
                                              int* __restrict__ e01,
                                              float* __restrict__ w01) {
  const int t = blockIdx.x * 4 + (threadIdx.x >> 6);
  const int lane = threadIdx.x & 63;
  const float* xr = x1 + (long)t * Dq;
  float acc[8];
  #pragma unroll
  for (int e = 0; e < 8; e++) acc[e] = 0.f;
  #pragma unroll
  for (int j = 0; j < 16; j++) {
    const int d = lane + 64 * j;
    const float xv = xr[d];
    const float4 g0 = *(const float4*)(gw + d * 8);
    const float4 g1 = *(const float4*)(gw + d * 8 + 4);
    acc[0] = fmaf(xv, g0.x, acc[0]);
    acc[1] = fmaf(xv, g0.y, acc[1]);
    acc[2] = fmaf(xv, g0.z, acc[2]);
    acc[3] = fmaf(xv, g0.w, acc[3]);
    acc[4] = fmaf(xv, g1.x, acc[4]);
    acc[5] = fmaf(xv, g1.y, acc[5]);
    acc[6] = fmaf(xv, g1.z, acc[6]);
    acc[7] = fmaf(xv, g1.w, acc[7]);
  }
  #pragma unroll
  for (int off = 32; off >= 1; off >>= 1)
    #pragma unroll
    for (int e = 0; e < 8; e++) acc[e] += __shfl_xor(acc[e], off, 64);
  if (lane == 0) {
    float mx = -1e30f;
    #pragma unroll
    for (int e = 0; e < 8; e++) { acc[e] += gb[e]; mx = fmaxf(mx, acc[e]); }
    float Z = 0.f, p[8];
    #pragma unroll
    for (int e = 0; e < 8; e++) { p[e] = __expf(acc[e] - mx); Z += p[e]; }
    const float invZ = 1.0f / Z;
    float b0 = -1.f, b1 = -1.f;
    int i0 = 0, i1 = 0;
    #pragma unroll
    for (int e = 0; e < 8; e++) {
      const float pe = p[e] * invZ;
      if (pe > b0) { b1 = b0; i1 = i0; b0 = pe; i0 = e; }
      else if (pe > b1) { b1 = pe; i1 = e; }
    }
    const float s = b0 + b1;
    e01[2 * t] = i0;
    e01[2 * t + 1] = i1;
    w01[2 * t] = b0 / s;
    w01[2 * t + 1] = b1 / s;
  }
}

__global__ void zero_k(int* p) {
  if (threadIdx.x < 16) p[threadIdx.x] = 0;
}

__global__ __launch_bounds__(256) void zerof_k(float* __restrict__ p) {
  const long i = ((long)blockIdx.x * 256 + threadIdx.x) * 4;
  *(float4*)(p + i) = make_float4(0.f, 0.f, 0.f, 0.f);
}

__global__ __launch_bounds__(256) void count_k(const int* __restrict__ e01,
                                               int* __restrict__ counts) {
  __shared__ int lc[8];
  const int tid = threadIdx.x;
  if (tid < 8) lc[tid] = 0;
  __syncthreads();
  const int t = blockIdx.x * 256 + tid;
  atomicAdd(&lc[e01[2 * t]], 1);
  atomicAdd(&lc[e01[2 * t + 1]], 1);
  __syncthreads();
  if (tid < 8) atomicAdd(&counts[tid], lc[tid]);
}

__global__ void offs_k(const int* __restrict__ counts, int* __restrict__ offsp) {
  if (threadIdx.x == 0) {
    int a = 0;
    for (int e = 0; e < 8; e++) {
      offsp[e] = a;
      a += ((counts[e] + 127) >> 7) << 7;
    }
    offsp[8] = a;
  }
}

__global__ __launch_bounds__(256) void scatter_k(
    const int* __restrict__ e01, const float* __restrict__ w01,
    int* __restrict__ cursor, const int* __restrict__ offsp,
    int* __restrict__ list, float* __restrict__ wslot) {
  __shared__ int lc[8];
  __shared__ int gbase[8];
  const int tid = threadIdx.x;
  if (tid < 8) lc[tid] = 0;
  __syncthreads();
  const int t = blockIdx.x * 256 + tid;
  const int e0 = e01[2 * t], e1 = e01[2 * t + 1];
  const int p0 = atomicAdd(&lc[e0], 1);
  const int p1 = atomicAdd(&lc[e1], 1);
  __syncthreads();
  if (tid < 8) gbase[tid] = atomicAdd(&cursor[tid], lc[tid]);
  __syncthreads();
  const int s0 = offsp[e0] + gbase[e0] + p0;
  const int s1 = offsp[e1] + gbase[e1] + p1;
  list[s0] = t;
  list[s1] = t;
  wslot[s0] = w01[2 * t];
  wslot[s1] = w01[2 * t + 1];
}

// ---------------------------------------------------------------------------
extern "C" void kernel_launch(void* const* d_in, const int* in_sizes, int n_in,
                              void* d_out, int out_size, void* d_ws,
                              size_t ws_size, hipStream_t stream) {
  const float* x          = (const float*)d_in[0];
  const float* conv_w     = (const float*)d_in[1];
  const float* conv_b     = (const float*)d_in[2];
  const float* in_proj_w  = (const float*)d_in[3];
  const float* in_proj_b  = (const float*)d_in[4];
  const float* out_proj_w = (const float*)d_in[5];
  const float* out_proj_b = (const float*)d_in[6];
  const float* ln1_g      = (const float*)d_in[7];
  const float* ln1_b      = (const float*)d_in[8];
  const float* gate_w     = (const float*)d_in[9];
  const float* gate_b     = (const float*)d_in[10];
  const float* w1         = (const float*)d_in[11];
  const float* b1         = (const float*)d_in[12];
  const float* w2         = (const float*)d_in[13];
  const float* b2         = (const float*)d_in[14];
  const float* ln2_g      = (const float*)d_in[15];
  const float* ln2_b      = (const float*)d_in[16];

  float* ws = (float*)d_ws;
  char* wsb = (char*)d_ws;
  int* si      = (int*)ws;
  int* counts  = si;
  int* cursor  = si + 8;
  int* offsp   = si + 16;
  int* e01     = si + 32;
  float* w01   = (float*)(si + 32 + 2 * Tq);
  int* list    = si + 32 + 4 * Tq;
  float* wslot = (float*)(list + PADT);

  float* xc   = ws + OFF_XC;      // conv out (A) / moe accumulator (B)
  float* moe  = ws + OFF_XC;
  float* qc   = ws + OFF_Q;       // qkv chunk fp32 (A)
  u16* wtx    = (u16*)(ws + OFF_WT);   // split-pair f16 weights (A), reused
  u16* h      = (u16*)(wsb + H_B);     // MoE hidden bf16 (B)
  u16* w1be   = (u16*)(wsb + W1E_B);   // per-expert bf16 weights (B)
  u16* w2be   = (u16*)(wsb + W2E_B);
  float* o    = (float*)d_out;    // attn out -> x1 -> final out
  float* x1   = (float*)d_out;
  float* out  = (float*)d_out;

  zero_k<<<1, 64, 0, stream>>>(counts);
  // conv weight -> split-pair f16 [768][1024][8]
  wsplit_conv<<<dim3(4, 768), 256, 0, stream>>>(conv_w, wtx);
  // conv as GEMM (fp32-accuracy f16 split): xc = shift(x) @ wt + conv_b
  gemm_h<1, 0><<<dim3(Dq / BN, Tq / BM), 256, 0, stream>>>(
      x, wtx, conv_b, xc, 3 * Dq, Dq, Dq, Dq, 0);
  // in_proj weight -> split-pair [256][3072][8]
  wsplit_nk<<<dim3(12, 256), 256, 0, stream>>>(in_proj_w, wtx, 3 * Dq, Dq);
  // qkv + attention, 4 seq chunks of 1024
  for (int c = 0; c < Sq / QCN; c++) {
    gemm_h<4, 0><<<dim3(3 * Dq / BN, QROWS / BM), 256, 0, stream>>>(
        xc, wtx, in_proj_b, qc, Dq, Dq, 3 * Dq, 3 * Dq, c * QCN);
    attn_k<<<(QCN * Hq) / 4, 256, 0, stream>>>(qc, o, c * QCN);
  }
  // out_proj weight -> split-pair [256][1024][8]
  wsplit_nk<<<dim3(4, 256), 256, 0, stream>>>(out_proj_w, wtx, Dq, Dq);
  // attn-out projection accumulated into xc
  gemm_h<0, 2><<<dim3(Dq / BN, Tq / BM), 256, 0, stream>>>(
      o, wtx, out_proj_b, xc, Dq, Dq, Dq, Dq, 0);
  // x1 = LN1(xc) into d_out
  ln1_k<<<Tq, 256, 0, stream>>>(xc, ln1_g, ln1_b, x1);
  // moe accumulator = 0 (overlays dead xc)
  zerof_k<<<Tq, 256, 0, stream>>>(moe);
  // gating + compaction (fp32 x1 — selection bit-stable vs reference)
  gate_k<<<Tq / 4, 256, 0, stream>>>(x1, gate_w, gate_b, e01, w01);
  count_k<<<Tq / 256, 256, 0, stream>>>(e01, counts);
  offs_k<<<1, 64, 0, stream>>>(counts, offsp);
  scatter_k<<<Tq / 256, 256, 0, stream>>>(e01, w01, cursor, offsp, list, wslot);
  // MoE: per-expert bf16 weight streaming + MFMA GEMMs
  for (int e = 0; e < Eq; e++) {
    kn2b_k<<<dim3(HIDq / 256, Dq / 8), 256, 0, stream>>>(
        w1 + (long)e * Dq * HIDq, w1be, HIDq);
    kn2b_k<<<dim3(Dq / 256, HIDq / 8), 256, 0, stream>>>(
        w2 + (long)e * HIDq * Dq, w2be, Dq);
    for (int c = 0; c < MAXC; c++) {
      gemm_b<5, 1><<<dim3(HIDq / BN, ECH / BM), 256, 0, stream>>>(
          x1, w1be, b1 + (long)e * HIDq, h, Dq, Dq, HIDq, HIDq,
          list, wslot, offsp, counts, nullptr, e, c * ECH);
      gemm_b<6, 3><<<dim3(Dq / BN, ECH / BM), 256, 0, stream>>>(
          h, w2be, b2 + (long)e * Dq, nullptr, HIDq, HIDq, Dq, Dq,
          list, wslot, offsp, counts, moe, e, c * ECH);
    }
  }
  // out = LN2(x1 + moe)
  ln2_k<<<Tq, 256, 0, stream>>>(x1, moe, ln2_g, ln2_b, out);
}

// Round 12
// 3380.394 us; speedup vs baseline: 1.2456x; 1.0753x over previous
//
#include <hip/hip_runtime.h>

typedef unsigned short u16;
typedef unsigned int u32;
typedef __attribute__((ext_vector_type(8))) short bf16x8;
typedef __attribute__((ext_vector_type(8))) _Float16 f16x8;
typedef __attribute__((ext_vector_type(4))) float f32x4;

// ---------------------------------------------------------------------------
// Problem constants
// ---------------------------------------------------------------------------
constexpr int Bq = 4, Sq = 4096, Dq = 1024, Hq = 16, Eq = 8, HIDq = 4096;
constexpr int Tq = Bq * Sq;               // 16384 tokens
constexpr long TD = (long)Tq * Dq;        // 16,777,216
constexpr int PADT = 33792;               // padded MoE slots cap
constexpr int QCN  = 1024;                // seq chunk for qkv/attn
constexpr int QROWS = 4 * QCN;
constexpr int GCH  = 4096;                // MoE global-slot chunk rows
constexpr int NCH  = 9;                   // ceil(PADT / GCH)

// ---------------------------------------------------------------------------
// Workspace layout (unchanged, proven safe).
// ---------------------------------------------------------------------------
constexpr long OFF_XC = 262144;                        // floats
constexpr long OFF_Q  = OFF_XC + TD;                   // floats
constexpr long OFF_WT = OFF_Q + (long)QROWS * 3 * Dq;  // floats
constexpr long H_B    = OFF_Q * 4;                     // bytes (h: 4096x4096 bf16)

// ---------------------------------------------------------------------------
// bf16 helpers (RNE)
// ---------------------------------------------------------------------------
__device__ __forceinline__ u32 bf1(float x) {
  u32 u = __builtin_bit_cast(u32, x);
  return (u + 0x7fffu + ((u >> 16) & 1u)) >> 16;
}
__device__ __forceinline__ u32 bfpk(float lo, float hi) {
  return bf1(lo) | (bf1(hi) << 16);
}

// ---------------------------------------------------------------------------
// f16 split helpers: a = ah + al*2^-12; al stored pre-scaled by 2^12.
// ---------------------------------------------------------------------------
__device__ __forceinline__ u16 f16b(float v) {
  _Float16 h = (_Float16)v;
  return __builtin_bit_cast(u16, h);
}
// A-side cross pair: [al_s | ah<<16]
__device__ __forceinline__ u32 axpk(float v) {
  _Float16 h = (_Float16)v;
  float hf = (float)h;
  u16 l = f16b((v - hf) * 4096.0f);
  return (u32)l | ((u32)__builtin_bit_cast(u16, h) << 16);
}
// B-side stored pair: [bh | bl_s<<16]
__device__ __forceinline__ u32 bxpk(float v) {
  _Float16 h = (_Float16)v;
  float hf = (float)h;
  u16 l = f16b((v - hf) * 4096.0f);
  return (u32)__builtin_bit_cast(u16, h) | ((u32)l << 16);
}

#define BM 128
#define BN 128

// async global->LDS, 16B per lane (dest = wave-uniform base + lane*16)
#define GLL16(SRC, DST)                                                \
  __builtin_amdgcn_global_load_lds(                                    \
      (const __attribute__((address_space(1))) void*)(SRC),            \
      (__attribute__((address_space(3))) void*)(DST), 16, 0, 0)

// ---------------------------------------------------------------------------
// XCD-aware block swizzle (kept: FETCH 807->230 MB measured R9).
// ---------------------------------------------------------------------------
__device__ __forceinline__ void xcd_swz(int& bx, int& by) {
  const int nbx = (int)gridDim.x;
  const int nwg = nbx * (int)gridDim.y;
  int bid = (int)blockIdx.y * nbx + (int)blockIdx.x;
  bid = (bid & 7) * (nwg >> 3) + (bid >> 3);
  bx = bid % nbx;
  by = bid / nbx;
}

// ---------------------------------------------------------------------------
// Octet extraction from split-pair quads in LDS.
// ---------------------------------------------------------------------------
__device__ __forceinline__ f16x8 hi_octet(const u16* p) {
  const uint4 a = *(const uint4*)p;
  const uint4 b = *(const uint4*)(p + 1024);  // next quad-row block
  uint4 r;
  r.x = __builtin_amdgcn_perm(a.y, a.x, 0x07060302u);
  r.y = __builtin_amdgcn_perm(a.w, a.z, 0x07060302u);
  r.z = __builtin_amdgcn_perm(b.y, b.x, 0x07060302u);
  r.w = __builtin_amdgcn_perm(b.w, b.z, 0x07060302u);
  return __builtin_bit_cast(f16x8, r);
}
__device__ __forceinline__ f16x8 lo_octet(const u16* p) {
  const uint4 a = *(const uint4*)p;
  const uint4 b = *(const uint4*)(p + 1024);
  uint4 r;
  r.x = __builtin_amdgcn_perm(a.y, a.x, 0x05040100u);
  r.y = __builtin_amdgcn_perm(a.w, a.z, 0x05040100u);
  r.z = __builtin_amdgcn_perm(b.y, b.x, 0x05040100u);
  r.w = __builtin_amdgcn_perm(b.w, b.z, 0x05040100u);
  return __builtin_bit_cast(f16x8, r);
}

// ===========================================================================
// f16 split-precision MFMA GEMM, SINGLE-PASS + SOFTWARE-PIPELINED STAGING
// (R10-measured 487->439 us, kept unchanged).
// AMODE: 0 direct rows | 1 conv-gather from x | 4 qkv-chunk gather from xc
// EPI:   0 bias store | 2 bias + C_old accumulate store
// ===========================================================================
template <int AMODE, int EPI>
__global__ __launch_bounds__(256, 2) void gemm_h(
    const float* __restrict__ A, const u16* __restrict__ Bx,
    const float* __restrict__ bias, float* __restrict__ C,
    int Ko, int lda, int ldbN, int ldc, int nbase) {
  // quad-granular layouts: [quad 0..7][row 0..127][8 u16 = 4 pairs]
  __shared__ __align__(16) u16 Asx[8 * 128 * 8];
  __shared__ __align__(16) u16 Bsx[2][8 * 128 * 8];

  const int tid = threadIdx.x;
  int sbx, sby;
  xcd_swz(sbx, sby);
  const int m0 = sby * BM;
  const int n0 = sbx * BN;

  const float* arp[2];
  int abat[2], asrow[2];
  #pragma unroll
  for (int i = 0; i < 2; i++) {
    const int f = tid + 256 * i;
    const int m = f >> 2;
    if (AMODE == 0) {
      arp[i] = A + (long)(m0 + m) * lda;
    } else if (AMODE == 1) {
      abat[i] = (m0 + m) >> 12;
      asrow[i] = (m0 + m) & 4095;
    } else {  // AMODE == 4
      const int mm = m0 + m;
      const int l = mm >> 10;
      const int n = nbase + (mm & 1023);
      arp[i] = A + (long)(l * Sq + n) * lda;
    }
  }

  f32x4 acch[4][4], accx[4][4];
  #pragma unroll
  for (int i = 0; i < 4; i++)
    #pragma unroll
    for (int j = 0; j < 4; j++) {
      acch[i][j] = (f32x4)(0.f);
      accx[i][j] = (f32x4)(0.f);
    }

  const int lane = tid & 63;
  const int wave = tid >> 6;
  const int wr = wave >> 1, wc = wave & 1;
  const int q = lane >> 4, l16 = lane & 15;
  const int abase = wr * 64 + l16;
  const int bbase = wc * 64 + l16;

  // A-step load into registers (8 fp32 per thread-iter, 16 VGPRs total)
  auto loadA = [&](int k0, float4 v0[2], float4 v1[2]) {
    #pragma unroll
    for (int i = 0; i < 2; i++) {
      const int f = tid + 256 * i;
      const int kc = f & 3;
      const int kk = k0 + kc * 8;
      float4 a0 = make_float4(0.f, 0.f, 0.f, 0.f), a1 = a0;
      if (AMODE == 1) {
        const int tap = kk >> 10, din = kk & 1023;
        const int sin = asrow[i] + tap - 1;
        if (sin >= 0 && sin < Sq) {
          const float* p = A + ((long)(abat[i] * Sq + sin) * Dq + din);
          a0 = *(const float4*)p;
          a1 = *(const float4*)(p + 4);
        }
      } else {
        a0 = *(const float4*)(arp[i] + kk);
        a1 = *(const float4*)(arp[i] + kk + 4);
      }
      v0[i] = a0;
      v1[i] = a1;
    }
  };

  // B-step async stage into Bsx[buf] (no VGPR round-trip)
  auto issueB = [&](int k0, int buf) {
    const int kq0 = k0 >> 2;  // quad chunk index in Bx
    #pragma unroll
    for (int i = 0; i < 2; i++) {
      const int f = tid + 256 * i;
      const int kcb = f >> 7, n = f & 127;  // kcb uniform per wave; n lane-linear
      const u16* bp = Bx + ((long)(kq0 + 2 * kcb) * ldbN + n0 + n) * 8;
      GLL16(bp, &Bsx[buf][((2 * kcb) * 128 + n) * 8]);
      GLL16(bp + (long)ldbN * 8, &Bsx[buf][((2 * kcb + 1) * 128 + n) * 8]);
    }
  };

  // ---- prologue: step-0 A regs + step-0 B async stage ----
  float4 pv0[2], pv1[2];
  loadA(0, pv0, pv1);
  issueB(0, 0);

  int cur = 0;
  for (int k0 = 0; k0 < Ko; k0 += 32) {
    // ---- convert prefetched A regs -> Asx (axpk pairs) ----
    #pragma unroll
    for (int i = 0; i < 2; i++) {
      const int f = tid + 256 * i;
      const int m = f >> 2, kc = f & 3;
      uint4 wa, wb;
      wa.x = axpk(pv0[i].x);
      wa.y = axpk(pv0[i].y);
      wa.z = axpk(pv0[i].z);
      wa.w = axpk(pv0[i].w);
      wb.x = axpk(pv1[i].x);
      wb.y = axpk(pv1[i].y);
      wb.z = axpk(pv1[i].z);
      wb.w = axpk(pv1[i].w);
      *(uint4*)&Asx[((2 * kc) * 128 + m) * 8] = wa;
      *(uint4*)&Asx[((2 * kc + 1) * 128 + m) * 8] = wb;
    }
    __syncthreads();  // Asx visible; Bsx[cur] drained at prev tail barrier
    const bool more = (k0 + 32 < Ko);
    if (more) {
      loadA(k0 + 32, pv0, pv1);   // reg loads: latency hides under MFMAs
      issueB(k0 + 32, cur ^ 1);   // async LDS stage into other buffer
    }
    {
      const u16* Bc = Bsx[cur];
      f16x8 af[4], bf[4];
      // hh: lane-group q covers octet q = quads (2q, 2q+1)
      #pragma unroll
      for (int mf = 0; mf < 4; mf++)
        af[mf] = hi_octet(&Asx[((2 * q) * 128 + abase + mf * 16) * 8]);
      #pragma unroll
      for (int nf = 0; nf < 4; nf++)
        bf[nf] = lo_octet(&Bc[((2 * q) * 128 + bbase + nf * 16) * 8]);
      #pragma unroll
      for (int mf = 0; mf < 4; mf++)
        #pragma unroll
        for (int nf = 0; nf < 4; nf++)
          acch[mf][nf] = __builtin_amdgcn_mfma_f32_16x16x32_f16(
              af[mf], bf[nf], acch[mf][nf], 0, 0, 0);
      // cross: set s covers original k [s*16, s*16+16) = quads s*4+q per lane
      #pragma unroll
      for (int s = 0; s < 2; s++) {
        #pragma unroll
        for (int mf = 0; mf < 4; mf++)
          af[mf] =
              *(const f16x8*)&Asx[((s * 4 + q) * 128 + abase + mf * 16) * 8];
        #pragma unroll
        for (int nf = 0; nf < 4; nf++)
          bf[nf] =
              *(const f16x8*)&Bc[((s * 4 + q) * 128 + bbase + nf * 16) * 8];
        #pragma unroll
        for (int mf = 0; mf < 4; mf++)
          #pragma unroll
          for (int nf = 0; nf < 4; nf++)
            accx[mf][nf] = __builtin_amdgcn_mfma_f32_16x16x32_f16(
                af[mf], bf[nf], accx[mf][nf], 0, 0, 0);
      }
    }
    __syncthreads();  // drains next-step gll (+A reg loads) under MFMA cover
    cur ^= 1;
  }

  float bcol[4];
  #pragma unroll
  for (int nf = 0; nf < 4; nf++) bcol[nf] = bias[n0 + wc * 64 + nf * 16 + l16];
  #pragma unroll
  for (int mf = 0; mf < 4; mf++) {
    #pragma unroll
    for (int reg = 0; reg < 4; reg++) {
      const int row = wr * 64 + mf * 16 + q * 4 + reg;
      float* crow = C + (long)(m0 + row) * ldc;
      #pragma unroll
      for (int nf = 0; nf < 4; nf++) {
        const int col = n0 + wc * 64 + nf * 16 + l16;
        float v = acch[mf][nf][reg] + accx[mf][nf][reg] * (1.0f / 4096.0f) +
                  bcol[nf];
        if (EPI == 2) v += crow[col];
        crow[col] = v;
      }
    }
  }
}

// ===========================================================================
// MoE GEMMs, GLOBAL-SLOT-CHUNKED (all experts in one launch). offsp[] entries
// are 128-aligned, so each 128-row block belongs to exactly one expert.
// Weights read DIRECTLY from fp32 (on-the-fly bf16 convert; kn2b eliminated;
// values identical RNE).
// gemm_w1: h[slot-cbase] = relu(x1[list[slot]] @ w1[e] + b1[e])   grid (32,32)
// gemm_w2: moe[tok] += wgt * (h @ w2[e] + b2[e]); K split 4x1024 (kseg in by),
//          partials combined via atomicAdd (R6: atomics neutral). grid (8,128)
// ===========================================================================
__global__ __launch_bounds__(256) void gemm_w1(
    const float* __restrict__ x1, const float* __restrict__ w1,
    const float* __restrict__ b1, u16* __restrict__ h,
    const int* __restrict__ list, const int* __restrict__ offsp,
    const int* __restrict__ counts, int cbase) {
  __shared__ __align__(16) u16 As[8 * 128 * 8];
  __shared__ __align__(16) u16 Bs[8 * 128 * 8];

  const int tid = threadIdx.x;
  int sbx, sby;
  xcd_swz(sbx, sby);
  const int r0 = cbase + sby * BM;  // global slot base (128-aligned)
  if (r0 >= offsp[8]) return;
  int e = 0;
  #pragma unroll
  for (int t = 0; t < 7; t++)
    if (r0 >= offsp[t + 1]) e = t + 1;
  const int ebase = offsp[e];
  const int ecnt = counts[e];
  const int n0 = sbx * BN;
  const float* Bw = w1 + (long)e * Dq * HIDq;  // [k][n], k<1024, n<4096
  const float* bias = b1 + (long)e * HIDq;

  const float* aptr[4];
  bool aval[4];
  #pragma unroll
  for (int i = 0; i < 4; i++) {
    const int f = tid + 256 * i;
    const int m = f >> 3;
    aval[i] = (r0 + m - ebase) < ecnt;
    const int tok = aval[i] ? list[r0 + m] : 0;
    aptr[i] = x1 + (long)tok * Dq;
  }

  f32x4 acc[4][4];
  #pragma unroll
  for (int i = 0; i < 4; i++)
    #pragma unroll
    for (int j = 0; j < 4; j++) acc[i][j] = (f32x4)(0.f);

  const int lane = tid & 63;
  const int wave = tid >> 6;
  const int wr = wave >> 1, wc = wave & 1;
  const int q = lane >> 4, l16 = lane & 15;

  for (int k0 = 0; k0 < Dq; k0 += 64) {
    #pragma unroll
    for (int i = 0; i < 4; i++) {
      const int f = tid + 256 * i;
      const int m = f >> 3, kc = f & 7;
      const int kk = k0 + kc * 8;
      float4 v0 = make_float4(0.f, 0.f, 0.f, 0.f), v1 = v0;
      if (aval[i]) {
        v0 = *(const float4*)(aptr[i] + kk);
        v1 = *(const float4*)(aptr[i] + kk + 4);
      }
      uint4 w;
      w.x = bfpk(v0.x, v0.y);
      w.y = bfpk(v0.z, v0.w);
      w.z = bfpk(v1.x, v1.y);
      w.w = bfpk(v1.z, v1.w);
      *(uint4*)&As[(kc * 128 + m) * 8] = w;
    }
    #pragma unroll
    for (int i = 0; i < 4; i++) {
      const int f = tid + 256 * i;
      const int kcb = f >> 7, n = f & 127;
      const float* bp = Bw + (long)(k0 + kcb * 8) * HIDq + n0 + n;
      float v[8];
      #pragma unroll
      for (int j = 0; j < 8; j++) v[j] = bp[(long)j * HIDq];
      uint4 w;
      w.x = bfpk(v[0], v[1]);
      w.y = bfpk(v[2], v[3]);
      w.z = bfpk(v[4], v[5]);
      w.w = bfpk(v[6], v[7]);
      *(uint4*)&Bs[(kcb * 128 + n) * 8] = w;
    }
    __syncthreads();
    #pragma unroll
    for (int s = 0; s < 2; s++) {
      bf16x8 af[4], bfr[4];
      #pragma unroll
      for (int mf = 0; mf < 4; mf++)
        af[mf] = *(const bf16x8*)
            &As[((s * 4 + q) * 128 + wr * 64 + mf * 16 + l16) * 8];
      #pragma unroll
      for (int nf = 0; nf < 4; nf++)
        bfr[nf] = *(const bf16x8*)
            &Bs[((s * 4 + q) * 128 + wc * 64 + nf * 16 + l16) * 8];
      #pragma unroll
      for (int mf = 0; mf < 4; mf++)
        #pragma unroll
        for (int nf = 0; nf < 4; nf++)
          acc[mf][nf] = __builtin_amdgcn_mfma_f32_16x16x32_bf16(
              af[mf], bfr[nf], acc[mf][nf], 0, 0, 0);
    }
    __syncthreads();
  }

  const int lrow0 = r0 - cbase;  // chunk-local row base (0..3968)
  float bcol[4];
  #pragma unroll
  for (int nf = 0; nf < 4; nf++) bcol[nf] = bias[n0 + wc * 64 + nf * 16 + l16];
  #pragma unroll
  for (int mf = 0; mf < 4; mf++) {
    #pragma unroll
    for (int reg = 0; reg < 4; reg++) {
      const int row = wr * 64 + mf * 16 + q * 4 + reg;
      if ((r0 + row - ebase) >= ecnt) continue;
      #pragma unroll
      for (int nf = 0; nf < 4; nf++) {
        float v = fmaxf(acc[mf][nf][reg] + bcol[nf], 0.f);
        const int col = n0 + wc * 64 + nf * 16 + l16;
        h[(long)(lrow0 + row) * HIDq + col] = (u16)bf1(v);
      }
    }
  }
}

__global__ __launch_bounds__(256) void gemm_w2(
    const u16* __restrict__ h, const float* __restrict__ w2,
    const float* __restrict__ b2, float* __restrict__ moe,
    const int* __restrict__ list, const float* __restrict__ wslot,
    const int* __restrict__ offsp, const int* __restrict__ counts,
    int cbase) {
  __shared__ __align__(16) u16 As[8 * 128 * 8];
  __shared__ __align__(16) u16 Bs[8 * 128 * 8];

  const int tid = threadIdx.x;
  int sbx, sby;
  xcd_swz(sbx, sby);             // grid (8, 128)
  const int kseg = sby >> 5;     // 0..3 : K segment of 1024
  const int sblk = sby & 31;     // slot block within chunk
  const int r0 = cbase + sblk * BM;
  if (r0 >= offsp[8]) return;
  int e = 0;
  #pragma unroll
  for (int t = 0; t < 7; t++)
    if (r0 >= offsp[t + 1]) e = t + 1;
  const int ebase = offsp[e];
  const int ecnt = counts[e];
  const int n0 = sbx * BN;
  const int kstart = kseg * 1024;
  const float* Bw = w2 + (long)e * HIDq * Dq;  // [k][n], k<4096, n<1024
  const int lrow0 = r0 - cbase;

  f32x4 acc[4][4];
  #pragma unroll
  for (int i = 0; i < 4; i++)
    #pragma unroll
    for (int j = 0; j < 4; j++) acc[i][j] = (f32x4)(0.f);

  const int lane = tid & 63;
  const int wave = tid >> 6;
  const int wr = wave >> 1, wc = wave & 1;
  const int q = lane >> 4, l16 = lane & 15;

  for (int k0 = kstart; k0 < kstart + 1024; k0 += 64) {
    #pragma unroll
    for (int i = 0; i < 4; i++) {
      const int f = tid + 256 * i;
      const int m = f >> 3, kc = f & 7;
      const int kk = k0 + kc * 8;
      const uint4 w =
          *(const uint4*)(h + (long)(lrow0 + m) * HIDq + kk);
      *(uint4*)&As[(kc * 128 + m) * 8] = w;
    }
    #pragma unroll
    for (int i = 0; i < 4; i++) {
      const int f = tid + 256 * i;
      const int kcb = f >> 7, n = f & 127;
      const float* bp = Bw + (long)(k0 + kcb * 8) * Dq + n0 + n;
      float v[8];
      #pragma unroll
      for (int j = 0; j < 8; j++) v[j] = bp[(long)j * Dq];
      uint4 w;
      w.x = bfpk(v[0], v[1]);
      w.y = bfpk(v[2], v[3]);
      w.z = bfpk(v[4], v[5]);
      w.w = bfpk(v[6], v[7]);
      *(uint4*)&Bs[(kcb * 128 + n) * 8] = w;
    }
    __syncthreads();
    #pragma unroll
    for (int s = 0; s < 2; s++) {
      bf16x8 af[4], bfr[4];
      #pragma unroll
      for (int mf = 0; mf < 4; mf++)
        af[mf] = *(const bf16x8*)
            &As[((s * 4 + q) * 128 + wr * 64 + mf * 16 + l16) * 8];
      #pragma unroll
      for (int nf = 0; nf < 4; nf++)
        bfr[nf] = *(const bf16x8*)
            &Bs[((s * 4 + q) * 128 + wc * 64 + nf * 16 + l16) * 8];
      #pragma unroll
      for (int mf = 0; mf < 4; mf++)
        #pragma unroll
        for (int nf = 0; nf < 4; nf++)
          acc[mf][nf] = __builtin_amdgcn_mfma_f32_16x16x32_bf16(
              af[mf], bfr[nf], acc[mf][nf], 0, 0, 0);
    }
    __syncthreads();
  }

  float bcol[4];
  #pragma unroll
  for (int nf = 0; nf < 4; nf++)
    bcol[nf] = (kseg == 0)
                   ? b2[(long)e * Dq + n0 + wc * 64 + nf * 16 + l16]
                   : 0.f;
  #pragma unroll
  for (int mf = 0; mf < 4; mf++) {
    #pragma unroll
    for (int reg = 0; reg < 4; reg++) {
      const int row = wr * 64 + mf * 16 + q * 4 + reg;
      if ((r0 + row - ebase) >= ecnt) continue;
      const int tok = list[r0 + row];
      const float wgt = wslot[r0 + row];
      #pragma unroll
      for (int nf = 0; nf < 4; nf++) {
        const float v = acc[mf][nf][reg] + bcol[nf];
        const int col = n0 + wc * 64 + nf * 16 + l16;
        atomicAdd(moe + (long)tok * Dq + col, wgt * v);
      }
    }
  }
}

// ---------------------------------------------------------------------------
// conv_w (D,D,3) -> split-pair layout [kc=768][1024][8], k = tap*1024 + din
// ---------------------------------------------------------------------------
__global__ __launch_bounds__(256) void wsplit_conv(const float* __restrict__ cw,
                                                   u16* __restrict__ dst) {
  const int n = blockIdx.x * 256 + threadIdx.x;  // dout
  const int kc = blockIdx.y;                     // 0..767
  uint4 w;
  u32* wp = (u32*)&w;
  #pragma unroll
  for (int j = 0; j < 4; j++) {
    const int k = kc * 4 + j;
    const int tap = k >> 10, din = k & 1023;
    wp[j] = bxpk(cw[(long)n * 3072 + din * 3 + tap]);
  }
  *(uint4*)(dst + ((long)kc * 1024 + n) * 8) = w;
}

// N x K fp32 row-major (W with x @ W.T semantics) -> split-pair [K/4][N][8]
__global__ __launch_bounds__(256) void wsplit_nk(const float* __restrict__ src,
                                                 u16* __restrict__ dst, int N,
                                                 int K) {
  const int n = blockIdx.x * 256 + threadIdx.x;
  const int kc = blockIdx.y;  // 0..K/4-1
  const float4 v = *(const float4*)(src + (long)n * K + kc * 4);
  uint4 w;
  w.x = bxpk(v.x);
  w.y = bxpk(v.y);
  w.z = bxpk(v.z);
  w.w = bxpk(v.w);
  *(uint4*)(dst + ((long)kc * N + n) * 8) = w;
}

// ---------------------------------------------------------------------------
// Attention on a seq chunk (fp32 qc): one wave per (n,h); lane = d.
// ---------------------------------------------------------------------------
__global__ __launch_bounds__(256) void attn_k(const float* __restrict__ qc,
                                              float* __restrict__ o, int nbase) {
  const int wid = blockIdx.x * 4 + (threadIdx.x >> 6);
  const int lane = threadIdx.x & 63;
  const int h = wid & 15;
  const int nl = wid >> 4;
  float q[4], k[4], v[4];
  #pragma unroll
  for (int l = 0; l < 4; l++) {
    const long base = (long)(l * QCN + nl) * 3072 + h * 64 + lane;
    q[l] = qc[base];
    k[l] = qc[base + Dq];
    v[l] = qc[base + 2 * Dq];
  }
  float sc[4][4];
  #pragma unroll
  for (int l = 0; l < 4; l++)
    #pragma unroll
    for (int m = 0; m < 4; m++) sc[l][m] = q[l] * k[m];
  #pragma unroll
  for (int off = 32; off >= 1; off >>= 1)
    #pragma unroll
    for (int l = 0; l < 4; l++)
      #pragma unroll
      for (int m = 0; m < 4; m++) sc[l][m] += __shfl_xor(sc[l][m], off, 64);
  float p[4][4];
  #pragma unroll
  for (int l = 0; l < 4; l++) {
    float s0[4], mx = -1e30f;
    #pragma unroll
    for (int m = 0; m < 4; m++) { s0[m] = sc[l][m] * 0.125f; mx = fmaxf(mx, s0[m]); }
    float sum = 0.f;
    #pragma unroll
    for (int m = 0; m < 4; m++) { p[l][m] = __expf(s0[m] - mx); sum += p[l][m]; }
    const float inv = 1.0f / sum;
    #pragma unroll
    for (int m = 0; m < 4; m++) p[l][m] *= inv;
  }
  #pragma unroll
  for (int l = 0; l < 4; l++) {
    float ov = 0.f;
    #pragma unroll
    for (int m = 0; m < 4; m++) ov = fmaf(p[l][m], v[m], ov);
    o[(long)(l * Sq + nbase + nl) * Dq + h * 64 + lane] = ov;
  }
}

// ---------------------------------------------------------------------------
// LayerNorm
// ---------------------------------------------------------------------------
__device__ __forceinline__ float block_sum256(float v, float* sbuf) {
  #pragma unroll
  for (int off = 32; off >= 1; off >>= 1) v += __shfl_xor(v, off, 64);
  const int w = threadIdx.x >> 6;
  __syncthreads();
  if ((threadIdx.x & 63) == 0) sbuf[w] = v;
  __syncthreads();
  return sbuf[0] + sbuf[1] + sbuf[2] + sbuf[3];
}

__device__ __forceinline__ void ln_core(const float xv[4], const float* g,
                                        const float* bb, float* outp, long base,
                                        float* sbuf) {
  const float tot = block_sum256(xv[0] + xv[1] + xv[2] + xv[3], sbuf);
  const float mean = tot * (1.0f / 1024.0f);
  const float d0 = xv[0] - mean, d1 = xv[1] - mean, d2 = xv[2] - mean,
              d3 = xv[3] - mean;
  const float var =
      block_sum256(d0 * d0 + d1 * d1 + d2 * d2 + d3 * d3, sbuf) * (1.0f / 1024.0f);
  const float inv = 1.0f / sqrtf(var + 1e-5f);
  const int c = threadIdx.x * 4;
  const float4 gg = *(const float4*)(g + c);
  const float4 bv = *(const float4*)(bb + c);
  float4 r;
  r.x = d0 * inv * gg.x + bv.x;
  r.y = d1 * inv * gg.y + bv.y;
  r.z = d2 * inv * gg.z + bv.z;
  r.w = d3 * inv * gg.w + bv.w;
  *(float4*)(outp + base) = r;
}

__global__ __launch_bounds__(256) void ln1_k(const float* __restrict__ xc,
                                             const float* __restrict__ g,
                                             const float* __restrict__ bb,
                                             float* __restrict__ outp) {
  __shared__ float sbuf[4];
  const long base = (long)blockIdx.x * Dq + threadIdx.x * 4;
  const float4 a = *(const float4*)(xc + base);
  const float xv[4] = {a.x, a.y, a.z, a.w};
  ln_core(xv, g, bb, outp, base, sbuf);
}

__global__ __launch_bounds__(256) void ln2_k(const float* __restrict__ x1,
                                             const float* __restrict__ moe,
                                             const float* __restrict__ g,
                                             const float* __restrict__ bb,
                                             float* __restrict__ outp) {
  __shared__ float sbuf[4];
  const long base = (long)blockIdx.x * Dq + threadIdx.x * 4;
  const float4 a = *(const float4*)(x1 + base);
  const float4 m = *(const float4*)(moe + base);
  const float xv[4] = {a.x + m.x, a.y + m.y, a.z + m.z, a.w + m.w};
  ln_core(xv, g, bb, outp, base, sbuf);
}

// ---------------------------------------------------------------------------
// MoE gating + compaction (fp32 x1 — selection bit-stable vs reference)
// ---------------------------------------------------------------------------
__global__ __launch_bounds__(256) void gate_k(const float* __restrict__ x1,
                                              const float* __restrict__ gw,
                                              const float* __restrict__ gb,
                                              int* __restrict__ e01,
                                              float* __restrict__ w01) {
  const int t = blockIdx.x * 4 + (threadIdx.x >> 6);
  const int lane = threadIdx.x & 63;
  const float* xr = x1 + (long)t * Dq;
  float acc[8];
  #pragma unroll
  for (int e = 0; e < 8; e++) acc[e] = 0.f;
  #pragma unroll
  for (int j = 0; j < 16; j++) {
    const int d = lane + 64 * j;
    const float xv = xr[d];
    const float4 g0 = *(const float4*)(gw + d * 8);
    const float4 g1 = *(const float4*)(gw + d * 8 + 4);
    acc[0] = fmaf(xv, g0.x, acc[0]);
    acc[1] = fmaf(xv, g0.y, acc[1]);
    acc[2] = fmaf(xv, g0.z, acc[2]);
    acc[3] = fmaf(xv, g0.w, acc[3]);
    acc[4] = fmaf(xv, g1.x, acc[4]);
    acc[5] = fmaf(xv, g1.y, acc[5]);
    acc[6] = fmaf(xv, g1.z, acc[6]);
    acc[7] = fmaf(xv, g1.w, acc[7]);
  }
  #pragma unroll
  for (int off = 32; off >= 1; off >>= 1)
    #pragma unroll
    for (int e = 0; e < 8; e++) acc[e] += __shfl_xor(acc[e], off, 64);
  if (lane == 0) {
    float mx = -1e30f;
    #pragma unroll
    for (int e = 0; e < 8; e++) { acc[e] += gb[e]; mx = fmaxf(mx, acc[e]); }
    float Z = 0.f, p[8];
    #pragma unroll
    for (int e = 0; e < 8; e++) { p[e] = __expf(acc[e] - mx); Z += p[e]; }
    const float invZ = 1.0f / Z;
    float b0 = -1.f, b1 = -1.f;
    int i0 = 0, i1 = 0;
    #pragma unroll
    for (int e = 0; e < 8; e++) {
      const float pe = p[e] * invZ;
      if (pe > b0) { b1 = b0; i1 = i0; b0 = pe; i0 = e; }
      else if (pe > b1) { b1 = pe; i1 = e; }
    }
    const float s = b0 + b1;
    e01[2 * t] = i0;
    e01[2 * t + 1] = i1;
    w01[2 * t] = b0 / s;
    w01[2 * t + 1] = b1 / s;
  }
}

__global__ void zero_k(int* p) {
  if (threadIdx.x < 16) p[threadIdx.x] = 0;
}

__global__ __launch_bounds__(256) void zerof_k(float* __restrict__ p) {
  const long i = ((long)blockIdx.x * 256 + threadIdx.x) * 4;
  *(float4*)(p + i) = make_float4(0.f, 0.f, 0.f, 0.f);
}

__global__ __launch_bounds__(256) void count_k(const int* __restrict__ e01,
                                               int* __restrict__ counts) {
  __shared__ int lc[8];
  const int tid = threadIdx.x;
  if (tid < 8) lc[tid] = 0;
  __syncthreads();
  const int t = blockIdx.x * 256 + tid;
  atomicAdd(&lc[e01[2 * t]], 1);
  atomicAdd(&lc[e01[2 * t + 1]], 1);
  __syncthreads();
  if (tid < 8) atomicAdd(&counts[tid], lc[tid]);
}

__global__ void offs_k(const int* __restrict__ counts, int* __restrict__ offsp) {
  if (threadIdx.x == 0) {
    int a = 0;
    for (int e = 0; e < 8; e++) {
      offsp[e] = a;
      a += ((counts[e] + 127) >> 7) << 7;
    }
    offsp[8] = a;
  }
}

__global__ __launch_bounds__(256) void scatter_k(
    const int* __restrict__ e01, const float* __restrict__ w01,
    int* __restrict__ cursor, const int* __restrict__ offsp,
    int* __restrict__ list, float* __restrict__ wslot) {
  __shared__ int lc[8];
  __shared__ int gbase[8];
  const int tid = threadIdx.x;
  if (tid < 8) lc[tid] = 0;
  __syncthreads();
  const int t = blockIdx.x * 256 + tid;
  const int e0 = e01[2 * t], e1 = e01[2 * t + 1];
  const int p0 = atomicAdd(&lc[e0], 1);
  const int p1 = atomicAdd(&lc[e1], 1);
  __syncthreads();
  if (tid < 8) gbase[tid] = atomicAdd(&cursor[tid], lc[tid]);
  __syncthreads();
  const int s0 = offsp[e0] + gbase[e0] + p0;
  const int s1 = offsp[e1] + gbase[e1] + p1;
  list[s0] = t;
  list[s1] = t;
  wslot[s0] = w01[2 * t];
  wslot[s1] = w01[2 * t + 1];
}

// ---------------------------------------------------------------------------
extern "C" void kernel_launch(void* const* d_in, const int* in_sizes, int n_in,
                              void* d_out, int out_size, void* d_ws,
                              size_t ws_size, hipStream_t stream) {
  const float* x          = (const float*)d_in[0];
  const float* conv_w     = (const float*)d_in[1];
  const float* conv_b     = (const float*)d_in[2];
  const float* in_proj_w  = (const float*)d_in[3];
  const float* in_proj_b  = (const float*)d_in[4];
  const float* out_proj_w = (const float*)d_in[5];
  const float* out_proj_b = (const float*)d_in[6];
  const float* ln1_g      = (const float*)d_in[7];
  const float* ln1_b      = (const float*)d_in[8];
  const float* gate_w     = (const float*)d_in[9];
  const float* gate_b     = (const float*)d_in[10];
  const float* w1         = (const float*)d_in[11];
  const float* b1         = (const float*)d_in[12];
  const float* w2         = (const float*)d_in[13];
  const float* b2         = (const float*)d_in[14];
  const float* ln2_g      = (const float*)d_in[15];
  const float* ln2_b      = (const float*)d_in[16];

  float* ws = (float*)d_ws;
  char* wsb = (char*)d_ws;
  int* si      = (int*)ws;
  int* counts  = si;
  int* cursor  = si + 8;
  int* offsp   = si + 16;
  int* e01     = si + 32;
  float* w01   = (float*)(si + 32 + 2 * Tq);
  int* list    = si + 32 + 4 * Tq;
  float* wslot = (float*)(list + PADT);

  float* xc   = ws + OFF_XC;      // conv out (A) / moe accumulator (B)
  float* moe  = ws + OFF_XC;
  float* qc   = ws + OFF_Q;       // qkv chunk fp32 (A)
  u16* wtx    = (u16*)(ws + OFF_WT);   // split-pair f16 weights (A), reused
  u16* h      = (u16*)(wsb + H_B);     // MoE hidden bf16, one 4096-slot chunk
  float* o    = (float*)d_out;    // attn out -> x1 -> final out
  float* x1   = (float*)d_out;
  float* out  = (float*)d_out;

  zero_k<<<1, 64, 0, stream>>>(counts);
  // conv weight -> split-pair f16 [768][1024][8]
  wsplit_conv<<<dim3(4, 768), 256, 0, stream>>>(conv_w, wtx);
  // conv as GEMM (fp32-accuracy f16 split): xc = shift(x) @ wt + conv_b
  gemm_h<1, 0><<<dim3(Dq / BN, Tq / BM), 256, 0, stream>>>(
      x, wtx, conv_b, xc, 3 * Dq, Dq, Dq, Dq, 0);
  // in_proj weight -> split-pair [256][3072][8]
  wsplit_nk<<<dim3(12, 256), 256, 0, stream>>>(in_proj_w, wtx, 3 * Dq, Dq);
  // qkv + attention, 4 seq chunks of 1024
  for (int c = 0; c < Sq / QCN; c++) {
    gemm_h<4, 0><<<dim3(3 * Dq / BN, QROWS / BM), 256, 0, stream>>>(
        xc, wtx, in_proj_b, qc, Dq, Dq, 3 * Dq, 3 * Dq, c * QCN);
    attn_k<<<(QCN * Hq) / 4, 256, 0, stream>>>(qc, o, c * QCN);
  }
  // out_proj weight -> split-pair [256][1024][8]
  wsplit_nk<<<dim3(4, 256), 256, 0, stream>>>(out_proj_w, wtx, Dq, Dq);
  // attn-out projection accumulated into xc
  gemm_h<0, 2><<<dim3(Dq / BN, Tq / BM), 256, 0, stream>>>(
      o, wtx, out_proj_b, xc, Dq, Dq, Dq, Dq, 0);
  // x1 = LN1(xc) into d_out
  ln1_k<<<Tq, 256, 0, stream>>>(xc, ln1_g, ln1_b, x1);
  // moe accumulator = 0 (overlays dead xc)
  zerof_k<<<Tq, 256, 0, stream>>>(moe);
  // gating + compaction (fp32 x1 — selection bit-stable vs reference)
  gate_k<<<Tq / 4, 256, 0, stream>>>(x1, gate_w, gate_b, e01, w01);
  count_k<<<Tq / 256, 256, 0, stream>>>(e01, counts);
  offs_k<<<1, 64, 0, stream>>>(counts, offsp);
  scatter_k<<<Tq / 256, 256, 0, stream>>>(e01, w01, cursor, offsp, list, wslot);
  // MoE: global-slot chunks, experts batched per launch, fp32 weights direct
  for (int c = 0; c < NCH; c++) {
    gemm_w1<<<dim3(HIDq / BN, GCH / BM), 256, 0, stream>>>(
        x1, w1, b1, h, list, offsp, counts, c * GCH);
    gemm_w2<<<dim3(Dq / BN, 4 * (GCH / BM)), 256, 0, stream>>>(
        h, w2, b2, moe, list, wslot, offsp, counts, c * GCH);
  }
  // out = LN2(x1 + moe)
  ln2_k<<<Tq, 256, 0, stream>>>(x1, moe, ln2_g, ln2_b, out);
}

// Round 13
// 3270.424 us; speedup vs baseline: 1.2875x; 1.0336x over previous
//
#include <hip/hip_runtime.h>

typedef unsigned short u16;
typedef unsigned int u32;
typedef __attribute__((ext_vector_type(8))) short bf16x8;
typedef __attribute__((ext_vector_type(8))) _Float16 f16x8;
typedef __attribute__((ext_vector_type(4))) float f32x4;

// ---------------------------------------------------------------------------
// Problem constants
// ---------------------------------------------------------------------------
constexpr int Bq = 4, Sq = 4096, Dq = 1024, Hq = 16, Eq = 8, HIDq = 4096;
constexpr int Tq = Bq * Sq;               // 16384 tokens
constexpr long TD = (long)Tq * Dq;        // 16,777,216
constexpr int PADT = 33792;               // padded MoE slots cap
constexpr int QCN  = 1024;                // seq chunk for qkv/attn
constexpr int QROWS = 4 * QCN;
constexpr int GCH  = 4096;                // MoE global-slot chunk rows
constexpr int NCH  = 9;                   // ceil(PADT / GCH)

// ---------------------------------------------------------------------------
// Workspace layout. Phase A peak 131 MB (proven). Phase B: h at H_B (33.5MB).
// OPTIONAL (ws_size-gated): all-expert bf16 weights after h:
//   w1ball at H_B+33.5MB (67.1MB), w2ball next (67.1MB) -> high-water 236MB.
// ---------------------------------------------------------------------------
constexpr long OFF_XC = 262144;                        // floats
constexpr long OFF_Q  = OFF_XC + TD;                   // floats
constexpr long OFF_WT = OFF_Q + (long)QROWS * 3 * Dq;  // floats
constexpr long H_B    = OFF_Q * 4;                     // bytes (h: 4096x4096 bf16)
constexpr long W1B_B  = H_B + 33554432L;               // bytes
constexpr long W2B_B  = W1B_B + 67108864L;             // bytes
constexpr unsigned long long WS_BIG = (unsigned long long)(W2B_B + 67108864L);

// ---------------------------------------------------------------------------
// bf16 helpers (RNE)
// ---------------------------------------------------------------------------
__device__ __forceinline__ u32 bf1(float x) {
  u32 u = __builtin_bit_cast(u32, x);
  return (u + 0x7fffu + ((u >> 16) & 1u)) >> 16;
}
__device__ __forceinline__ u32 bfpk(float lo, float hi) {
  return bf1(lo) | (bf1(hi) << 16);
}

// ---------------------------------------------------------------------------
// f16 split helpers: a = ah + al*2^-12; al stored pre-scaled by 2^12.
// ---------------------------------------------------------------------------
__device__ __forceinline__ u16 f16b(float v) {
  _Float16 h = (_Float16)v;
  return __builtin_bit_cast(u16, h);
}
// A-side cross pair: [al_s | ah<<16]
__device__ __forceinline__ u32 axpk(float v) {
  _Float16 h = (_Float16)v;
  float hf = (float)h;
  u16 l = f16b((v - hf) * 4096.0f);
  return (u32)l | ((u32)__builtin_bit_cast(u16, h) << 16);
}
// B-side stored pair: [bh | bl_s<<16]
__device__ __forceinline__ u32 bxpk(float v) {
  _Float16 h = (_Float16)v;
  float hf = (float)h;
  u16 l = f16b((v - hf) * 4096.0f);
  return (u32)__builtin_bit_cast(u16, h) | ((u32)l << 16);
}

#define BM 128
#define BN 128

// async global->LDS, 16B per lane (dest = wave-uniform base + lane*16)
#define GLL16(SRC, DST)                                                \
  __builtin_amdgcn_global_load_lds(                                    \
      (const __attribute__((address_space(1))) void*)(SRC),            \
      (__attribute__((address_space(3))) void*)(DST), 16, 0, 0)

// ---------------------------------------------------------------------------
// XCD-aware block swizzle (kept: FETCH 807->230 MB measured R9).
// ---------------------------------------------------------------------------
__device__ __forceinline__ void xcd_swz(int& bx, int& by) {
  const int nbx = (int)gridDim.x;
  const int nwg = nbx * (int)gridDim.y;
  int bid = (int)blockIdx.y * nbx + (int)blockIdx.x;
  bid = (bid & 7) * (nwg >> 3) + (bid >> 3);
  bx = bid % nbx;
  by = bid / nbx;
}

// ---------------------------------------------------------------------------
// Octet extraction from split-pair quads in LDS.
// ---------------------------------------------------------------------------
__device__ __forceinline__ f16x8 hi_octet(const u16* p) {
  const uint4 a = *(const uint4*)p;
  const uint4 b = *(const uint4*)(p + 1024);  // next quad-row block
  uint4 r;
  r.x = __builtin_amdgcn_perm(a.y, a.x, 0x07060302u);
  r.y = __builtin_amdgcn_perm(a.w, a.z, 0x07060302u);
  r.z = __builtin_amdgcn_perm(b.y, b.x, 0x07060302u);
  r.w = __builtin_amdgcn_perm(b.w, b.z, 0x07060302u);
  return __builtin_bit_cast(f16x8, r);
}
__device__ __forceinline__ f16x8 lo_octet(const u16* p) {
  const uint4 a = *(const uint4*)p;
  const uint4 b = *(const uint4*)(p + 1024);
  uint4 r;
  r.x = __builtin_amdgcn_perm(a.y, a.x, 0x05040100u);
  r.y = __builtin_amdgcn_perm(a.w, a.z, 0x05040100u);
  r.z = __builtin_amdgcn_perm(b.y, b.x, 0x05040100u);
  r.w = __builtin_amdgcn_perm(b.w, b.z, 0x05040100u);
  return __builtin_bit_cast(f16x8, r);
}

// ===========================================================================
// f16 split-precision MFMA GEMM, SINGLE-PASS + SOFTWARE-PIPELINED STAGING
// (R10-measured 487->439 us, kept unchanged).
// AMODE: 0 direct rows | 1 conv-gather from x | 4 qkv-chunk gather from xc
// EPI:   0 bias store | 2 bias + C_old accumulate store
// ===========================================================================
template <int AMODE, int EPI>
__global__ __launch_bounds__(256, 2) void gemm_h(
    const float* __restrict__ A, const u16* __restrict__ Bx,
    const float* __restrict__ bias, float* __restrict__ C,
    int Ko, int lda, int ldbN, int ldc, int nbase) {
  // quad-granular layouts: [quad 0..7][row 0..127][8 u16 = 4 pairs]
  __shared__ __align__(16) u16 Asx[8 * 128 * 8];
  __shared__ __align__(16) u16 Bsx[2][8 * 128 * 8];

  const int tid = threadIdx.x;
  int sbx, sby;
  xcd_swz(sbx, sby);
  const int m0 = sby * BM;
  const int n0 = sbx * BN;

  const float* arp[2];
  int abat[2], asrow[2];
  #pragma unroll
  for (int i = 0; i < 2; i++) {
    const int f = tid + 256 * i;
    const int m = f >> 2;
    if (AMODE == 0) {
      arp[i] = A + (long)(m0 + m) * lda;
    } else if (AMODE == 1) {
      abat[i] = (m0 + m) >> 12;
      asrow[i] = (m0 + m) & 4095;
    } else {  // AMODE == 4
      const int mm = m0 + m;
      const int l = mm >> 10;
      const int n = nbase + (mm & 1023);
      arp[i] = A + (long)(l * Sq + n) * lda;
    }
  }

  f32x4 acch[4][4], accx[4][4];
  #pragma unroll
  for (int i = 0; i < 4; i++)
    #pragma unroll
    for (int j = 0; j < 4; j++) {
      acch[i][j] = (f32x4)(0.f);
      accx[i][j] = (f32x4)(0.f);
    }

  const int lane = tid & 63;
  const int wave = tid >> 6;
  const int wr = wave >> 1, wc = wave & 1;
  const int q = lane >> 4, l16 = lane & 15;
  const int abase = wr * 64 + l16;
  const int bbase = wc * 64 + l16;

  // A-step load into registers (8 fp32 per thread-iter, 16 VGPRs total)
  auto loadA = [&](int k0, float4 v0[2], float4 v1[2]) {
    #pragma unroll
    for (int i = 0; i < 2; i++) {
      const int f = tid + 256 * i;
      const int kc = f & 3;
      const int kk = k0 + kc * 8;
      float4 a0 = make_float4(0.f, 0.f, 0.f, 0.f), a1 = a0;
      if (AMODE == 1) {
        const int tap = kk >> 10, din = kk & 1023;
        const int sin = asrow[i] + tap - 1;
        if (sin >= 0 && sin < Sq) {
          const float* p = A + ((long)(abat[i] * Sq + sin) * Dq + din);
          a0 = *(const float4*)p;
          a1 = *(const float4*)(p + 4);
        }
      } else {
        a0 = *(const float4*)(arp[i] + kk);
        a1 = *(const float4*)(arp[i] + kk + 4);
      }
      v0[i] = a0;
      v1[i] = a1;
    }
  };

  // B-step async stage into Bsx[buf] (no VGPR round-trip)
  auto issueB = [&](int k0, int buf) {
    const int kq0 = k0 >> 2;  // quad chunk index in Bx
    #pragma unroll
    for (int i = 0; i < 2; i++) {
      const int f = tid + 256 * i;
      const int kcb = f >> 7, n = f & 127;  // kcb uniform per wave; n lane-linear
      const u16* bp = Bx + ((long)(kq0 + 2 * kcb) * ldbN + n0 + n) * 8;
      GLL16(bp, &Bsx[buf][((2 * kcb) * 128 + n) * 8]);
      GLL16(bp + (long)ldbN * 8, &Bsx[buf][((2 * kcb + 1) * 128 + n) * 8]);
    }
  };

  // ---- prologue: step-0 A regs + step-0 B async stage ----
  float4 pv0[2], pv1[2];
  loadA(0, pv0, pv1);
  issueB(0, 0);

  int cur = 0;
  for (int k0 = 0; k0 < Ko; k0 += 32) {
    // ---- convert prefetched A regs -> Asx (axpk pairs) ----
    #pragma unroll
    for (int i = 0; i < 2; i++) {
      const int f = tid + 256 * i;
      const int m = f >> 2, kc = f & 3;
      uint4 wa, wb;
      wa.x = axpk(pv0[i].x);
      wa.y = axpk(pv0[i].y);
      wa.z = axpk(pv0[i].z);
      wa.w = axpk(pv0[i].w);
      wb.x = axpk(pv1[i].x);
      wb.y = axpk(pv1[i].y);
      wb.z = axpk(pv1[i].z);
      wb.w = axpk(pv1[i].w);
      *(uint4*)&Asx[((2 * kc) * 128 + m) * 8] = wa;
      *(uint4*)&Asx[((2 * kc + 1) * 128 + m) * 8] = wb;
    }
    __syncthreads();  // Asx visible; Bsx[cur] drained at prev tail barrier
    const bool more = (k0 + 32 < Ko);
    if (more) {
      loadA(k0 + 32, pv0, pv1);   // reg loads: latency hides under MFMAs
      issueB(k0 + 32, cur ^ 1);   // async LDS stage into other buffer
    }
    {
      const u16* Bc = Bsx[cur];
      f16x8 af[4], bf[4];
      // hh: lane-group q covers octet q = quads (2q, 2q+1)
      #pragma unroll
      for (int mf = 0; mf < 4; mf++)
        af[mf] = hi_octet(&Asx[((2 * q) * 128 + abase + mf * 16) * 8]);
      #pragma unroll
      for (int nf = 0; nf < 4; nf++)
        bf[nf] = lo_octet(&Bc[((2 * q) * 128 + bbase + nf * 16) * 8]);
      #pragma unroll
      for (int mf = 0; mf < 4; mf++)
        #pragma unroll
        for (int nf = 0; nf < 4; nf++)
          acch[mf][nf] = __builtin_amdgcn_mfma_f32_16x16x32_f16(
              af[mf], bf[nf], acch[mf][nf], 0, 0, 0);
      // cross: set s covers original k [s*16, s*16+16) = quads s*4+q per lane
      #pragma unroll
      for (int s = 0; s < 2; s++) {
        #pragma unroll
        for (int mf = 0; mf < 4; mf++)
          af[mf] =
              *(const f16x8*)&Asx[((s * 4 + q) * 128 + abase + mf * 16) * 8];
        #pragma unroll
        for (int nf = 0; nf < 4; nf++)
          bf[nf] =
              *(const f16x8*)&Bc[((s * 4 + q) * 128 + bbase + nf * 16) * 8];
        #pragma unroll
        for (int mf = 0; mf < 4; mf++)
          #pragma unroll
          for (int nf = 0; nf < 4; nf++)
            accx[mf][nf] = __builtin_amdgcn_mfma_f32_16x16x32_f16(
                af[mf], bf[nf], accx[mf][nf], 0, 0, 0);
      }
    }
    __syncthreads();  // drains next-step gll (+A reg loads) under MFMA cover
    cur ^= 1;
  }

  float bcol[4];
  #pragma unroll
  for (int nf = 0; nf < 4; nf++) bcol[nf] = bias[n0 + wc * 64 + nf * 16 + l16];
  #pragma unroll
  for (int mf = 0; mf < 4; mf++) {
    #pragma unroll
    for (int reg = 0; reg < 4; reg++) {
      const int row = wr * 64 + mf * 16 + q * 4 + reg;
      float* crow = C + (long)(m0 + row) * ldc;
      #pragma unroll
      for (int nf = 0; nf < 4; nf++) {
        const int col = n0 + wc * 64 + nf * 16 + l16;
        float v = acch[mf][nf][reg] + accx[mf][nf][reg] * (1.0f / 4096.0f) +
                  bcol[nf];
        if (EPI == 2) v += crow[col];
        crow[col] = v;
      }
    }
  }
}

// ===========================================================================
// MoE GEMMs, GLOBAL-SLOT-CHUNKED (all experts in one launch). offsp[] entries
// are 128-aligned, so each 128-row block belongs to exactly one expert.
// BFMT=0: B read directly from fp32 weights (8 strided loads + pack).
// BFMT=1: B read from pre-converted bf16 [kc][n][8] (1 uint4 load) —
//         identical RNE values; enabled when ws_size permits.
// gemm_w1: h[slot-cbase] = relu(x1[list[slot]] @ w1[e] + b1[e])   grid (32,32)
// gemm_w2: moe[tok] += wgt * (h @ w2[e] + b2[e]); K split 4x1024 (kseg in by),
//          partials combined via atomicAdd (R6: atomics neutral). grid (8,128)
// ===========================================================================
template <int BFMT>
__global__ __launch_bounds__(256) void gemm_w1(
    const float* __restrict__ x1, const float* __restrict__ w1f,
    const u16* __restrict__ w1b, const float* __restrict__ b1,
    u16* __restrict__ h, const int* __restrict__ list,
    const int* __restrict__ offsp, const int* __restrict__ counts, int cbase) {
  __shared__ __align__(16) u16 As[8 * 128 * 8];
  __shared__ __align__(16) u16 Bs[8 * 128 * 8];

  const int tid = threadIdx.x;
  int sbx, sby;
  xcd_swz(sbx, sby);
  const int r0 = cbase + sby * BM;  // global slot base (128-aligned)
  if (r0 >= offsp[8]) return;
  int e = 0;
  #pragma unroll
  for (int t = 0; t < 7; t++)
    if (r0 >= offsp[t + 1]) e = t + 1;
  const int ebase = offsp[e];
  const int ecnt = counts[e];
  const int n0 = sbx * BN;
  const float* Bw = w1f + (long)e * Dq * HIDq;   // fp32 [k][n]
  const u16* Bc = w1b + (long)e * Dq * HIDq;     // bf16 [kc][n][8]
  const float* bias = b1 + (long)e * HIDq;

  const float* aptr[4];
  bool aval[4];
  #pragma unroll
  for (int i = 0; i < 4; i++) {
    const int f = tid + 256 * i;
    const int m = f >> 3;
    aval[i] = (r0 + m - ebase) < ecnt;
    const int tok = aval[i] ? list[r0 + m] : 0;
    aptr[i] = x1 + (long)tok * Dq;
  }

  f32x4 acc[4][4];
  #pragma unroll
  for (int i = 0; i < 4; i++)
    #pragma unroll
    for (int j = 0; j < 4; j++) acc[i][j] = (f32x4)(0.f);

  const int lane = tid & 63;
  const int wave = tid >> 6;
  const int wr = wave >> 1, wc = wave & 1;
  const int q = lane >> 4, l16 = lane & 15;

  for (int k0 = 0; k0 < Dq; k0 += 64) {
    #pragma unroll
    for (int i = 0; i < 4; i++) {
      const int f = tid + 256 * i;
      const int m = f >> 3, kc = f & 7;
      const int kk = k0 + kc * 8;
      float4 v0 = make_float4(0.f, 0.f, 0.f, 0.f), v1 = v0;
      if (aval[i]) {
        v0 = *(const float4*)(aptr[i] + kk);
        v1 = *(const float4*)(aptr[i] + kk + 4);
      }
      uint4 w;
      w.x = bfpk(v0.x, v0.y);
      w.y = bfpk(v0.z, v0.w);
      w.z = bfpk(v1.x, v1.y);
      w.w = bfpk(v1.z, v1.w);
      *(uint4*)&As[(kc * 128 + m) * 8] = w;
    }
    const int kc0 = k0 >> 3;
    #pragma unroll
    for (int i = 0; i < 4; i++) {
      const int f = tid + 256 * i;
      const int kcb = f >> 7, n = f & 127;
      uint4 w;
      if (BFMT == 1) {
        w = *(const uint4*)(Bc + ((long)(kc0 + kcb) * HIDq + n0 + n) * 8);
      } else {
        const float* bp = Bw + (long)(k0 + kcb * 8) * HIDq + n0 + n;
        float v[8];
        #pragma unroll
        for (int j = 0; j < 8; j++) v[j] = bp[(long)j * HIDq];
        w.x = bfpk(v[0], v[1]);
        w.y = bfpk(v[2], v[3]);
        w.z = bfpk(v[4], v[5]);
        w.w = bfpk(v[6], v[7]);
      }
      *(uint4*)&Bs[(kcb * 128 + n) * 8] = w;
    }
    __syncthreads();
    #pragma unroll
    for (int s = 0; s < 2; s++) {
      bf16x8 af[4], bfr[4];
      #pragma unroll
      for (int mf = 0; mf < 4; mf++)
        af[mf] = *(const bf16x8*)
            &As[((s * 4 + q) * 128 + wr * 64 + mf * 16 + l16) * 8];
      #pragma unroll
      for (int nf = 0; nf < 4; nf++)
        bfr[nf] = *(const bf16x8*)
            &Bs[((s * 4 + q) * 128 + wc * 64 + nf * 16 + l16) * 8];
      #pragma unroll
      for (int mf = 0; mf < 4; mf++)
        #pragma unroll
        for (int nf = 0; nf < 4; nf++)
          acc[mf][nf] = __builtin_amdgcn_mfma_f32_16x16x32_bf16(
              af[mf], bfr[nf], acc[mf][nf], 0, 0, 0);
    }
    __syncthreads();
  }

  const int lrow0 = r0 - cbase;  // chunk-local row base (0..3968)
  float bcol[4];
  #pragma unroll
  for (int nf = 0; nf < 4; nf++) bcol[nf] = bias[n0 + wc * 64 + nf * 16 + l16];
  #pragma unroll
  for (int mf = 0; mf < 4; mf++) {
    #pragma unroll
    for (int reg = 0; reg < 4; reg++) {
      const int row = wr * 64 + mf * 16 + q * 4 + reg;
      if ((r0 + row - ebase) >= ecnt) continue;
      #pragma unroll
      for (int nf = 0; nf < 4; nf++) {
        float v = fmaxf(acc[mf][nf][reg] + bcol[nf], 0.f);
        const int col = n0 + wc * 64 + nf * 16 + l16;
        h[(long)(lrow0 + row) * HIDq + col] = (u16)bf1(v);
      }
    }
  }
}

template <int BFMT>
__global__ __launch_bounds__(256) void gemm_w2(
    const u16* __restrict__ h, const float* __restrict__ w2f,
    const u16* __restrict__ w2b, const float* __restrict__ b2,
    float* __restrict__ moe, const int* __restrict__ list,
    const float* __restrict__ wslot, const int* __restrict__ offsp,
    const int* __restrict__ counts, int cbase) {
  __shared__ __align__(16) u16 As[8 * 128 * 8];
  __shared__ __align__(16) u16 Bs[8 * 128 * 8];

  const int tid = threadIdx.x;
  int sbx, sby;
  xcd_swz(sbx, sby);             // grid (8, 128)
  const int kseg = sby >> 5;     // 0..3 : K segment of 1024
  const int sblk = sby & 31;     // slot block within chunk
  const int r0 = cbase + sblk * BM;
  if (r0 >= offsp[8]) return;
  int e = 0;
  #pragma unroll
  for (int t = 0; t < 7; t++)
    if (r0 >= offsp[t + 1]) e = t + 1;
  const int ebase = offsp[e];
  const int ecnt = counts[e];
  const int n0 = sbx * BN;
  const int kstart = kseg * 1024;
  const float* Bw = w2f + (long)e * HIDq * Dq;   // fp32 [k][n]
  const u16* Bc = w2b + (long)e * HIDq * Dq;     // bf16 [kc][n][8]
  const int lrow0 = r0 - cbase;

  f32x4 acc[4][4];
  #pragma unroll
  for (int i = 0; i < 4; i++)
    #pragma unroll
    for (int j = 0; j < 4; j++) acc[i][j] = (f32x4)(0.f);

  const int lane = tid & 63;
  const int wave = tid >> 6;
  const int wr = wave >> 1, wc = wave & 1;
  const int q = lane >> 4, l16 = lane & 15;

  for (int k0 = kstart; k0 < kstart + 1024; k0 += 64) {
    #pragma unroll
    for (int i = 0; i < 4; i++) {
      const int f = tid + 256 * i;
      const int m = f >> 3, kc = f & 7;
      const int kk = k0 + kc * 8;
      const uint4 w =
          *(const uint4*)(h + (long)(lrow0 + m) * HIDq + kk);
      *(uint4*)&As[(kc * 128 + m) * 8] = w;
    }
    const int kc0 = k0 >> 3;
    #pragma unroll
    for (int i = 0; i < 4; i++) {
      const int f = tid + 256 * i;
      const int kcb = f >> 7, n = f & 127;
      uint4 w;
      if (BFMT == 1) {
        w = *(const uint4*)(Bc + ((long)(kc0 + kcb) * Dq + n0 + n) * 8);
      } else {
        const float* bp = Bw + (long)(k0 + kcb * 8) * Dq + n0 + n;
        float v[8];
        #pragma unroll
        for (int j = 0; j < 8; j++) v[j] = bp[(long)j * Dq];
        w.x = bfpk(v[0], v[1]);
        w.y = bfpk(v[2], v[3]);
        w.z = bfpk(v[4], v[5]);
        w.w = bfpk(v[6], v[7]);
      }
      *(uint4*)&Bs[(kcb * 128 + n) * 8] = w;
    }
    __syncthreads();
    #pragma unroll
    for (int s = 0; s < 2; s++) {
      bf16x8 af[4], bfr[4];
      #pragma unroll
      for (int mf = 0; mf < 4; mf++)
        af[mf] = *(const bf16x8*)
            &As[((s * 4 + q) * 128 + wr * 64 + mf * 16 + l16) * 8];
      #pragma unroll
      for (int nf = 0; nf < 4; nf++)
        bfr[nf] = *(const bf16x8*)
            &Bs[((s * 4 + q) * 128 + wc * 64 + nf * 16 + l16) * 8];
      #pragma unroll
      for (int mf = 0; mf < 4; mf++)
        #pragma unroll
        for (int nf = 0; nf < 4; nf++)
          acc[mf][nf] = __builtin_amdgcn_mfma_f32_16x16x32_bf16(
              af[mf], bfr[nf], acc[mf][nf], 0, 0, 0);
    }
    __syncthreads();
  }

  float bcol[4];
  #pragma unroll
  for (int nf = 0; nf < 4; nf++)
    bcol[nf] = (kseg == 0)
                   ? b2[(long)e * Dq + n0 + wc * 64 + nf * 16 + l16]
                   : 0.f;
  #pragma unroll
  for (int mf = 0; mf < 4; mf++) {
    #pragma unroll
    for (int reg = 0; reg < 4; reg++) {
      const int row = wr * 64 + mf * 16 + q * 4 + reg;
      if ((r0 + row - ebase) >= ecnt) continue;
      const int tok = list[r0 + row];
      const float wgt = wslot[r0 + row];
      #pragma unroll
      for (int nf = 0; nf < 4; nf++) {
        const float v = acc[mf][nf][reg] + bcol[nf];
        const int col = n0 + wc * 64 + nf * 16 + l16;
        atomicAdd(moe + (long)tok * Dq + col, wgt * v);
      }
    }
  }
}

// ---------------------------------------------------------------------------
// conv_w (D,D,3) -> split-pair layout [kc=768][1024][8], k = tap*1024 + din
// ---------------------------------------------------------------------------
__global__ __launch_bounds__(256) void wsplit_conv(const float* __restrict__ cw,
                                                   u16* __restrict__ dst) {
  const int n = blockIdx.x * 256 + threadIdx.x;  // dout
  const int kc = blockIdx.y;                     // 0..767
  uint4 w;
  u32* wp = (u32*)&w;
  #pragma unroll
  for (int j = 0; j < 4; j++) {
    const int k = kc * 4 + j;
    const int tap = k >> 10, din = k & 1023;
    wp[j] = bxpk(cw[(long)n * 3072 + din * 3 + tap]);
  }
  *(uint4*)(dst + ((long)kc * 1024 + n) * 8) = w;
}

// N x K fp32 row-major (W with x @ W.T semantics) -> split-pair [K/4][N][8]
__global__ __launch_bounds__(256) void wsplit_nk(const float* __restrict__ src,
                                                 u16* __restrict__ dst, int N,
                                                 int K) {
  const int n = blockIdx.x * 256 + threadIdx.x;
  const int kc = blockIdx.y;  // 0..K/4-1
  const float4 v = *(const float4*)(src + (long)n * K + kc * 4);
  uint4 w;
  w.x = bxpk(v.x);
  w.y = bxpk(v.y);
  w.z = bxpk(v.z);
  w.w = bxpk(v.w);
  *(uint4*)(dst + ((long)kc * N + n) * 8) = w;
}

// KxN fp32 (n contiguous) -> bf16 [kc][n][8]; grid (N/256, K/8)
__global__ __launch_bounds__(256) void kn2b_k(const float* __restrict__ src,
                                              u16* __restrict__ dst, int N) {
  const int n = blockIdx.x * 256 + threadIdx.x;
  const int kc = blockIdx.y;
  float v[8];
  #pragma unroll
  for (int j = 0; j < 8; j++) v[j] = src[(long)(kc * 8 + j) * N + n];
  uint4 w;
  w.x = bfpk(v[0], v[1]);
  w.y = bfpk(v[2], v[3]);
  w.z = bfpk(v[4], v[5]);
  w.w = bfpk(v[6], v[7]);
  *(uint4*)(dst + ((long)kc * N + n) * 8) = w;
}

// ---------------------------------------------------------------------------
// Attention on a seq chunk (fp32 qc): one wave per (n,h); lane = d.
// ---------------------------------------------------------------------------
__global__ __launch_bounds__(256) void attn_k(const float* __restrict__ qc,
                                              float* __restrict__ o, int nbase) {
  const int wid = blockIdx.x * 4 + (threadIdx.x >> 6);
  const int lane = threadIdx.x & 63;
  const int h = wid & 15;
  const int nl = wid >> 4;
  float q[4], k[4], v[4];
  #pragma unroll
  for (int l = 0; l < 4; l++) {
    const long base = (long)(l * QCN + nl) * 3072 + h * 64 + lane;
    q[l] = qc[base];
    k[l] = qc[base + Dq];
    v[l] = qc[base + 2 * Dq];
  }
  float sc[4][4];
  #pragma unroll
  for (int l = 0; l < 4; l++)
    #pragma unroll
    for (int m = 0; m < 4; m++) sc[l][m] = q[l] * k[m];
  #pragma unroll
  for (int off = 32; off >= 1; off >>= 1)
    #pragma unroll
    for (int l = 0; l < 4; l++)
      #pragma unroll
      for (int m = 0; m < 4; m++) sc[l][m] += __shfl_xor(sc[l][m], off, 64);
  float p[4][4];
  #pragma unroll
  for (int l = 0; l < 4; l++) {
    float s0[4], mx = -1e30f;
    #pragma unroll
    for (int m = 0; m < 4; m++) { s0[m] = sc[l][m] * 0.125f; mx = fmaxf(mx, s0[m]); }
    float sum = 0.f;
    #pragma unroll
    for (int m = 0; m < 4; m++) { p[l][m] = __expf(s0[m] - mx); sum += p[l][m]; }
    const float inv = 1.0f / sum;
    #pragma unroll
    for (int m = 0; m < 4; m++) p[l][m] *= inv;
  }
  #pragma unroll
  for (int l = 0; l < 4; l++) {
    float ov = 0.f;
    #pragma unroll
    for (int m = 0; m < 4; m++) ov = fmaf(p[l][m], v[m], ov);
    o[(long)(l * Sq + nbase + nl) * Dq + h * 64 + lane] = ov;
  }
}

// ---------------------------------------------------------------------------
// LayerNorm
// ---------------------------------------------------------------------------
__device__ __forceinline__ float block_sum256(float v, float* sbuf) {
  #pragma unroll
  for (int off = 32; off >= 1; off >>= 1) v += __shfl_xor(v, off, 64);
  const int w = threadIdx.x >> 6;
  __syncthreads();
  if ((threadIdx.x & 63) == 0) sbuf[w] = v;
  __syncthreads();
  return sbuf[0] + sbuf[1] + sbuf[2] + sbuf[3];
}

__device__ __forceinline__ void ln_core(const float xv[4], const float* g,
                                        const float* bb, float* outp, long base,
                                        float* sbuf) {
  const float tot = block_sum256(xv[0] + xv[1] + xv[2] + xv[3], sbuf);
  const float mean = tot * (1.0f / 1024.0f);
  const float d0 = xv[0] - mean, d1 = xv[1] - mean, d2 = xv[2] - mean,
              d3 = xv[3] - mean;
  const float var =
      block_sum256(d0 * d0 + d1 * d1 + d2 * d2 + d3 * d3, sbuf) * (1.0f / 1024.0f);
  const float inv = 1.0f / sqrtf(var + 1e-5f);
  const int c = threadIdx.x * 4;
  const float4 gg = *(const float4*)(g + c);
  const float4 bv = *(const float4*)(bb + c);
  float4 r;
  r.x = d0 * inv * gg.x + bv.x;
  r.y = d1 * inv * gg.y + bv.y;
  r.z = d2 * inv * gg.z + bv.z;
  r.w = d3 * inv * gg.w + bv.w;
  *(float4*)(outp + base) = r;
}

__global__ __launch_bounds__(256) void ln1_k(const float* __restrict__ xc,
                                             const float* __restrict__ g,
                                             const float* __restrict__ bb,
                                             float* __restrict__ outp) {
  __shared__ float sbuf[4];
  const long base = (long)blockIdx.x * Dq + threadIdx.x * 4;
  const float4 a = *(const float4*)(xc + base);
  const float xv[4] = {a.x, a.y, a.z, a.w};
  ln_core(xv, g, bb, outp, base, sbuf);
}

__global__ __launch_bounds__(256) void ln2_k(const float* __restrict__ x1,
                                             const float* __restrict__ moe,
                                             const float* __restrict__ g,
                                             const float* __restrict__ bb,
                                             float* __restrict__ outp) {
  __shared__ float sbuf[4];
  const long base = (long)blockIdx.x * Dq + threadIdx.x * 4;
  const float4 a = *(const float4*)(x1 + base);
  const float4 m = *(const float4*)(moe + base);
  const float xv[4] = {a.x + m.x, a.y + m.y, a.z + m.z, a.w + m.w};
  ln_core(xv, g, bb, outp, base, sbuf);
}

// ---------------------------------------------------------------------------
// MoE gating + compaction (fp32 x1 — selection bit-stable vs reference)
// ---------------------------------------------------------------------------
__global__ __launch_bounds__(256) void gate_k(const float* __restrict__ x1,
                                              const float* __restrict__ gw,
                                              const float* __restrict__ gb,
                                              int* __restrict__ e01,
                                              float* __restrict__ w01) {
  const int t = blockIdx.x * 4 + (threadIdx.x >> 6);
  const int lane = threadIdx.x & 63;
  const float* xr = x1 + (long)t * Dq;
  float acc[8];
  #pragma unroll
  for (int e = 0; e < 8; e++) acc[e] = 0.f;
  #pragma unroll
  for (int j = 0; j < 16; j++) {
    const int d = lane + 64 * j;
    const float xv = xr[d];
    const float4 g0 = *(const float4*)(gw + d * 8);
    const float4 g1 = *(const float4*)(gw + d * 8 + 4);
    acc[0] = fmaf(xv, g0.x, acc[0]);
    acc[1] = fmaf(xv, g0.y, acc[1]);
    acc[2] = fmaf(xv, g0.z, acc[2]);
    acc[3] = fmaf(xv, g0.w, acc[3]);
    acc[4] = fmaf(xv, g1.x, acc[4]);
    acc[5] = fmaf(xv, g1.y, acc[5]);
    acc[6] = fmaf(xv, g1.z, acc[6]);
    acc[7] = fmaf(xv, g1.w, acc[7]);
  }
  #pragma unroll
  for (int off = 32; off >= 1; off >>= 1)
    #pragma unroll
    for (int e = 0; e < 8; e++) acc[e] += __shfl_xor(acc[e], off, 64);
  if (lane == 0) {
    float mx = -1e30f;
    #pragma unroll
    for (int e = 0; e < 8; e++) { acc[e] += gb[e]; mx = fmaxf(mx, acc[e]); }
    float Z = 0.f, p[8];
    #pragma unroll
    for (int e = 0; e < 8; e++) { p[e] = __expf(acc[e] - mx); Z += p[e]; }
    const float invZ = 1.0f / Z;
    float b0 = -1.f, b1 = -1.f;
    int i0 = 0, i1 = 0;
    #pragma unroll
    for (int e = 0; e < 8; e++) {
      const float pe = p[e] * invZ;
      if (pe > b0) { b1 = b0; i1 = i0; b0 = pe; i0 = e; }
      else if (pe > b1) { b1 = pe; i1 = e; }
    }
    const float s = b0 + b1;
    e01[2 * t] = i0;
    e01[2 * t + 1] = i1;
    w01[2 * t] = b0 / s;
    w01[2 * t + 1] = b1 / s;
  }
}

__global__ void zero_k(int* p) {
  if (threadIdx.x < 16) p[threadIdx.x] = 0;
}

__global__ __launch_bounds__(256) void zerof_k(float* __restrict__ p) {
  const long i = ((long)blockIdx.x * 256 + threadIdx.x) * 4;
  *(float4*)(p + i) = make_float4(0.f, 0.f, 0.f, 0.f);
}

__global__ __launch_bounds__(256) void count_k(const int* __restrict__ e01,
                                               int* __restrict__ counts) {
  __shared__ int lc[8];
  const int tid = threadIdx.x;
  if (tid < 8) lc[tid] = 0;
  __syncthreads();
  const int t = blockIdx.x * 256 + tid;
  atomicAdd(&lc[e01[2 * t]], 1);
  atomicAdd(&lc[e01[2 * t + 1]], 1);
  __syncthreads();
  if (tid < 8) atomicAdd(&counts[tid], lc[tid]);
}

__global__ void offs_k(const int* __restrict__ counts, int* __restrict__ offsp) {
  if (threadIdx.x == 0) {
    int a = 0;
    for (int e = 0; e < 8; e++) {
      offsp[e] = a;
      a += ((counts[e] + 127) >> 7) << 7;
    }
    offsp[8] = a;
  }
}

__global__ __launch_bounds__(256) void scatter_k(
    const int* __restrict__ e01, const float* __restrict__ w01,
    int* __restrict__ cursor, const int* __restrict__ offsp,
    int* __restrict__ list, float* __restrict__ wslot) {
  __shared__ int lc[8];
  __shared__ int gbase[8];
  const int tid = threadIdx.x;
  if (tid < 8) lc[tid] = 0;
  __syncthreads();
  const int t = blockIdx.x * 256 + tid;
  const int e0 = e01[2 * t], e1 = e01[2 * t + 1];
  const int p0 = atomicAdd(&lc[e0], 1);
  const int p1 = atomicAdd(&lc[e1], 1);
  __syncthreads();
  if (tid < 8) gbase[tid] = atomicAdd(&cursor[tid], lc[tid]);
  __syncthreads();
  const int s0 = offsp[e0] + gbase[e0] + p0;
  const int s1 = offsp[e1] + gbase[e1] + p1;
  list[s0] = t;
  list[s1] = t;
  wslot[s0] = w01[2 * t];
  wslot[s1] = w01[2 * t + 1];
}

// ---------------------------------------------------------------------------
extern "C" void kernel_launch(void* const* d_in, const int* in_sizes, int n_in,
                              void* d_out, int out_size, void* d_ws,
                              size_t ws_size, hipStream_t stream) {
  const float* x          = (const float*)d_in[0];
  const float* conv_w     = (const float*)d_in[1];
  const float* conv_b     = (const float*)d_in[2];
  const float* in_proj_w  = (const float*)d_in[3];
  const float* in_proj_b  = (const float*)d_in[4];
  const float* out_proj_w = (const float*)d_in[5];
  const float* out_proj_b = (const float*)d_in[6];
  const float* ln1_g      = (const float*)d_in[7];
  const float* ln1_b      = (const float*)d_in[8];
  const float* gate_w     = (const float*)d_in[9];
  const float* gate_b     = (const float*)d_in[10];
  const float* w1         = (const float*)d_in[11];
  const float* b1         = (const float*)d_in[12];
  const float* w2         = (const float*)d_in[13];
  const float* b2         = (const float*)d_in[14];
  const float* ln2_g      = (const float*)d_in[15];
  const float* ln2_b      = (const float*)d_in[16];

  float* ws = (float*)d_ws;
  char* wsb = (char*)d_ws;
  int* si      = (int*)ws;
  int* counts  = si;
  int* cursor  = si + 8;
  int* offsp   = si + 16;
  int* e01     = si + 32;
  float* w01   = (float*)(si + 32 + 2 * Tq);
  int* list    = si + 32 + 4 * Tq;
  float* wslot = (float*)(list + PADT);

  float* xc   = ws + OFF_XC;      // conv out (A) / moe accumulator (B)
  float* moe  = ws + OFF_XC;
  float* qc   = ws + OFF_Q;       // qkv chunk fp32 (A)
  u16* wtx    = (u16*)(ws + OFF_WT);   // split-pair f16 weights (A), reused
  u16* h      = (u16*)(wsb + H_B);     // MoE hidden bf16, one 4096-slot chunk
  u16* w1ball = (u16*)(wsb + W1B_B);   // optional all-expert bf16 weights
  u16* w2ball = (u16*)(wsb + W2B_B);
  float* o    = (float*)d_out;    // attn out -> x1 -> final out
  float* x1   = (float*)d_out;
  float* out  = (float*)d_out;

  const bool bigws = (unsigned long long)ws_size >= WS_BIG;

  zero_k<<<1, 64, 0, stream>>>(counts);
  // conv weight -> split-pair f16 [768][1024][8]
  wsplit_conv<<<dim3(4, 768), 256, 0, stream>>>(conv_w, wtx);
  // conv as GEMM (fp32-accuracy f16 split): xc = shift(x) @ wt + conv_b
  gemm_h<1, 0><<<dim3(Dq / BN, Tq / BM), 256, 0, stream>>>(
      x, wtx, conv_b, xc, 3 * Dq, Dq, Dq, Dq, 0);
  // in_proj weight -> split-pair [256][3072][8]
  wsplit_nk<<<dim3(12, 256), 256, 0, stream>>>(in_proj_w, wtx, 3 * Dq, Dq);
  // qkv + attention, 4 seq chunks of 1024
  for (int c = 0; c < Sq / QCN; c++) {
    gemm_h<4, 0><<<dim3(3 * Dq / BN, QROWS / BM), 256, 0, stream>>>(
        xc, wtx, in_proj_b, qc, Dq, Dq, 3 * Dq, 3 * Dq, c * QCN);
    attn_k<<<(QCN * Hq) / 4, 256, 0, stream>>>(qc, o, c * QCN);
  }
  // out_proj weight -> split-pair [256][1024][8]
  wsplit_nk<<<dim3(4, 256), 256, 0, stream>>>(out_proj_w, wtx, Dq, Dq);
  // attn-out projection accumulated into xc
  gemm_h<0, 2><<<dim3(Dq / BN, Tq / BM), 256, 0, stream>>>(
      o, wtx, out_proj_b, xc, Dq, Dq, Dq, Dq, 0);
  // x1 = LN1(xc) into d_out
  ln1_k<<<Tq, 256, 0, stream>>>(xc, ln1_g, ln1_b, x1);
  // moe accumulator = 0 (overlays dead xc)
  zerof_k<<<Tq, 256, 0, stream>>>(moe);
  // gating + compaction (fp32 x1 — selection bit-stable vs reference)
  gate_k<<<Tq / 4, 256, 0, stream>>>(x1, gate_w, gate_b, e01, w01);
  count_k<<<Tq / 256, 256, 0, stream>>>(e01, counts);
  offs_k<<<1, 64, 0, stream>>>(counts, offsp);
  scatter_k<<<Tq / 256, 256, 0, stream>>>(e01, w01, cursor, offsp, list, wslot);
  // Optional: pre-convert ALL expert weights to bf16 (ws_size-gated).
  // w1 viewed as [8192][4096] k-major; w2 as [32768][1024].
  if (bigws) {
    kn2b_k<<<dim3(HIDq / 256, (Eq * Dq) / 8), 256, 0, stream>>>(w1, w1ball,
                                                                HIDq);
    kn2b_k<<<dim3(Dq / 256, (Eq * HIDq) / 8), 256, 0, stream>>>(w2, w2ball,
                                                                Dq);
  }
  // MoE: global-slot chunks, experts batched per launch
  for (int c = 0; c < NCH; c++) {
    if (bigws) {
      gemm_w1<1><<<dim3(HIDq / BN, GCH / BM), 256, 0, stream>>>(
          x1, w1, w1ball, b1, h, list, offsp, counts, c * GCH);
      gemm_w2<1><<<dim3(Dq / BN, 4 * (GCH / BM)), 256, 0, stream>>>(
          h, w2, w2ball, b2, moe, list, wslot, offsp, counts, c * GCH);
    } else {
      gemm_w1<0><<<dim3(HIDq / BN, GCH / BM), 256, 0, stream>>>(
          x1, w1, w1ball, b1, h, list, offsp, counts, c * GCH);
      gemm_w2<0><<<dim3(Dq / BN, 4 * (GCH / BM)), 256, 0, stream>>>(
          h, w2, w2ball, b2, moe, list, wslot, offsp, counts, c * GCH);
    }
  }
  // out = LN2(x1 + moe)
  ln2_k<<<Tq, 256, 0, stream>>>(x1, moe, ln2_g, ln2_b, out);
}